// Round 2
// baseline (7334.064 us; speedup 1.0000x reference)
//
#include <hip/hip_runtime.h>
#include <stdint.h>

namespace {

constexpr int B = 8, N = 2048, KNN = 20;
constexpr int NPART = 64;  // spread for partial-stat atomics

__global__ void transpose_x(const float* __restrict__ x, float* __restrict__ f) {
  int i = blockIdx.x * 256 + threadIdx.x;
  if (i >= B * N * 3) return;
  int c = i % 3, n = (i / 3) % N, b = i / (3 * N);
  f[i] = x[((size_t)b * 3 + c) * N + n];
}

// kNN with fp64 distances (difference formula == exact value of the reference's
// expand formula) so the selected index set matches the reference ordering.
template <int C>
__global__ void __launch_bounds__(256) knn_kernel(const float* __restrict__ feat,
                                                  int* __restrict__ idx) {
  __shared__ double dist[N];  // 16 KB
  __shared__ float fn[C];
  __shared__ double wv[4];
  __shared__ int wi[4];
  int bn = blockIdx.x, tid = threadIdx.x;
  int b = bn >> 11, n = bn & (N - 1);
  const float* fb = feat + (size_t)b * N * C;
  for (int c = tid; c < C; c += 256) fn[c] = fb[(size_t)n * C + c];
  __syncthreads();
  for (int m = tid; m < N; m += 256) {
    const float* fm = fb + (size_t)m * C;
    double acc = 0.0;
#pragma unroll 4
    for (int c = 0; c < C; c++) {
      double d = (double)fn[c] - (double)fm[c];
      acc = fma(d, d, acc);
    }
    dist[m] = acc;
  }
  __syncthreads();
  int lane = tid & 63, wid = tid >> 6;
  for (int it = 0; it < KNN; it++) {
    double bv = 1e300;
    int bi = N;
    for (int m = tid; m < N; m += 256) {
      double v = dist[m];
      if (v < bv) { bv = v; bi = m; }  // ascending + strict < => lowest index tie-break
    }
#pragma unroll
    for (int s = 32; s > 0; s >>= 1) {
      double ov = __shfl_down(bv, s, 64);
      int oi = __shfl_down(bi, s, 64);
      if (ov < bv || (ov == bv && oi < bi)) { bv = ov; bi = oi; }
    }
    if (lane == 0) { wv[wid] = bv; wi[wid] = bi; }
    __syncthreads();
    if (tid == 0) {
      double v0 = wv[0];
      int i0 = wi[0];
#pragma unroll
      for (int w = 1; w < 4; w++) {
        if (wv[w] < v0 || (wv[w] == v0 && wi[w] < i0)) { v0 = wv[w]; i0 = wi[w]; }
      }
      idx[(size_t)bn * KNN + it] = i0;
      dist[i0] = 1e300;
    }
    __syncthreads();
  }
}

// One workgroup (D threads) per (b,n). Computes h = relu(e@W + b) for k=20
// neighbors, tracks per-channel max/min over k, and accumulates batch stats.
template <int C, int D>
__global__ void __launch_bounds__(D) edgeconv(const float* __restrict__ feat,
                                              const int* __restrict__ idx,
                                              const float* __restrict__ W,
                                              const float* __restrict__ bias,
                                              float* __restrict__ hmax,
                                              float* __restrict__ hmin,
                                              double* __restrict__ sumP,
                                              double* __restrict__ sqP) {
  __shared__ float e[KNN][2 * C];
  __shared__ float xcs[C];
  int bn = blockIdx.x, tid = threadIdx.x;
  int b = bn >> 11;
  const float* fb = feat + (size_t)b * N * C;
  for (int c = tid; c < C; c += D) xcs[c] = feat[(size_t)bn * C + c];
  __syncthreads();
  for (int j = 0; j < KNN; j++) {
    int nb = idx[(size_t)bn * KNN + j];
    const float* fm = fb + (size_t)nb * C;
    for (int c = tid; c < C; c += D) {
      float xv = xcs[c];
      e[j][c] = xv;
      e[j][C + c] = fm[c] - xv;
    }
  }
  __syncthreads();
  float acc[KNN];
  float bv = bias[tid];
#pragma unroll
  for (int j = 0; j < KNN; j++) acc[j] = bv;
  for (int c = 0; c < 2 * C; c++) {
    float w = W[(size_t)c * D + tid];
#pragma unroll
    for (int j = 0; j < KNN; j++) acc[j] += e[j][c] * w;
  }
  float mx = -1e30f, mn = 1e30f;
  double s = 0.0, q = 0.0;
#pragma unroll
  for (int j = 0; j < KNN; j++) {
    float h = acc[j] > 0.f ? acc[j] : 0.f;
    mx = fmaxf(mx, h);
    mn = fminf(mn, h);
    s += (double)h;
    q += (double)h * (double)h;
  }
  hmax[(size_t)bn * D + tid] = mx;
  hmin[(size_t)bn * D + tid] = mn;
  int slot = bn & (NPART - 1);
  atomicAdd(&sumP[slot * D + tid], s);
  atomicAdd(&sqP[slot * D + tid], q);
}

__global__ void bn_finalize(const double* __restrict__ sumP, const double* __restrict__ sqP,
                            const float* __restrict__ g, const float* __restrict__ be,
                            float* __restrict__ scale, float* __restrict__ shift, int D,
                            double invM) {
  int d = blockIdx.x * 256 + threadIdx.x;
  if (d >= D) return;
  double s = 0.0, q = 0.0;
  for (int i = 0; i < NPART; i++) {
    s += sumP[i * D + d];
    q += sqP[i * D + d];
  }
  double mean = s * invM;
  double var = q * invM - mean * mean;
  double sc = (double)g[d] / sqrt(var + 1e-5);
  scale[d] = (float)sc;
  shift[d] = (float)((double)be[d] - mean * sc);
}

__global__ void bn_apply_max(const float* __restrict__ hmax, const float* __restrict__ hmin,
                             const float* __restrict__ scale, const float* __restrict__ shift,
                             float* __restrict__ out, int dmask, int total) {
  int i = blockIdx.x * 256 + threadIdx.x;
  if (i >= total) return;
  int d = i & dmask;
  float sc = scale[d];
  float v = sc >= 0.f ? hmax[i] : hmin[i];
  out[i] = v * sc + shift[d];
}

__global__ void __launch_bounds__(256) final_gemm(const float* __restrict__ x1,
                                                  const float* __restrict__ x2,
                                                  const float* __restrict__ x3,
                                                  const float* __restrict__ x4,
                                                  const float* __restrict__ W5,
                                                  const float* __restrict__ b5,
                                                  unsigned int* __restrict__ h5max,
                                                  unsigned int* __restrict__ h5min,
                                                  double* __restrict__ sumP,
                                                  double* __restrict__ sqP) {
  __shared__ float row[320];
  int bn = blockIdx.x, tid = threadIdx.x;
  for (int c = tid; c < 320; c += 256) {
    float v;
    if (c < 64) v = x1[(size_t)bn * 64 + c];
    else if (c < 128) v = x2[(size_t)bn * 64 + (c - 64)];
    else if (c < 192) v = x3[(size_t)bn * 64 + (c - 128)];
    else v = x4[(size_t)bn * 128 + (c - 192)];
    row[c] = v;
  }
  __syncthreads();
  float acc[4] = {b5[tid], b5[tid + 256], b5[tid + 512], b5[tid + 768]};
  for (int c = 0; c < 320; c++) {
    float r = row[c];
    const float* w = W5 + (size_t)c * 1024 + tid;
    acc[0] += r * w[0];
    acc[1] += r * w[256];
    acc[2] += r * w[512];
    acc[3] += r * w[768];
  }
  int b = bn >> 11;
  int slot = bn & (NPART - 1);
#pragma unroll
  for (int q = 0; q < 4; q++) {
    float h = acc[q] > 0.f ? acc[q] : 0.f;
    int ch = tid + q * 256;
    atomicMax(&h5max[(size_t)b * 1024 + ch], __float_as_uint(h));
    atomicMin(&h5min[(size_t)b * 1024 + ch], __float_as_uint(h));
    atomicAdd(&sumP[slot * 1024 + ch], (double)h);
    atomicAdd(&sqP[slot * 1024 + ch], (double)h * (double)h);
  }
}

__global__ void final_apply(const unsigned int* __restrict__ h5max,
                            const unsigned int* __restrict__ h5min,
                            const float* __restrict__ scale, const float* __restrict__ shift,
                            float* __restrict__ out) {
  int i = blockIdx.x * 256 + threadIdx.x;
  if (i >= B * 1024) return;
  int ch = i & 1023;
  float sc = scale[ch];
  float v = __uint_as_float(sc >= 0.f ? h5max[i] : h5min[i]);
  out[i] = v * sc + shift[ch];
}

}  // namespace

extern "C" void kernel_launch(void* const* d_in, const int* in_sizes, int n_in,
                              void* d_out, int out_size, void* d_ws, size_t ws_size,
                              hipStream_t stream) {
  const float* x = (const float*)d_in[0];
  const float *Wv[5], *bv[5], *gv[5], *bev[5];
  for (int i = 0; i < 5; i++) {
    Wv[i] = (const float*)d_in[1 + 4 * i];
    bv[i] = (const float*)d_in[2 + 4 * i];
    gv[i] = (const float*)d_in[3 + 4 * i];
    bev[i] = (const float*)d_in[4 + 4 * i];
  }

  char* ws = (char*)d_ws;
  size_t off = 0;
  auto alloc = [&](size_t bytes) {
    size_t r = off;
    off = (off + bytes + 255) & ~(size_t)255;
    return r;
  };
  float* feat0 = (float*)(ws + alloc((size_t)B * N * 3 * 4));
  int* idx = (int*)(ws + alloc((size_t)B * N * KNN * 4));
  float* x1 = (float*)(ws + alloc((size_t)B * N * 64 * 4));
  float* x2 = (float*)(ws + alloc((size_t)B * N * 64 * 4));
  float* x3 = (float*)(ws + alloc((size_t)B * N * 64 * 4));
  float* x4 = (float*)(ws + alloc((size_t)B * N * 128 * 4));
  float* hmax = (float*)(ws + alloc((size_t)B * N * 128 * 4));
  float* hmin = (float*)(ws + alloc((size_t)B * N * 128 * 4));
  double* sumP = (double*)(ws + alloc((size_t)NPART * 1024 * 8));
  double* sqP = (double*)(ws + alloc((size_t)NPART * 1024 * 8));
  float* scale = (float*)(ws + alloc(1024 * 4));
  float* shift = (float*)(ws + alloc(1024 * 4));
  unsigned int* h5max = (unsigned int*)(ws + alloc((size_t)B * 1024 * 4));
  unsigned int* h5min = (unsigned int*)(ws + alloc((size_t)B * 1024 * 4));

  const int BN = B * N;
  const double invMk = 1.0 / ((double)BN * KNN);

  transpose_x<<<(B * N * 3 + 255) / 256, 256, 0, stream>>>(x, feat0);

  // ---- block 1: C=3 -> D=64 ----
  knn_kernel<3><<<BN, 256, 0, stream>>>(feat0, idx);
  hipMemsetAsync(sumP, 0, NPART * 64 * 8, stream);
  hipMemsetAsync(sqP, 0, NPART * 64 * 8, stream);
  edgeconv<3, 64><<<BN, 64, 0, stream>>>(feat0, idx, Wv[0], bv[0], hmax, hmin, sumP, sqP);
  bn_finalize<<<1, 256, 0, stream>>>(sumP, sqP, gv[0], bev[0], scale, shift, 64, invMk);
  bn_apply_max<<<(BN * 64 + 255) / 256, 256, 0, stream>>>(hmax, hmin, scale, shift, x1, 63,
                                                          BN * 64);

  // ---- block 2: C=64 -> D=64 ----
  knn_kernel<64><<<BN, 256, 0, stream>>>(x1, idx);
  hipMemsetAsync(sumP, 0, NPART * 64 * 8, stream);
  hipMemsetAsync(sqP, 0, NPART * 64 * 8, stream);
  edgeconv<64, 64><<<BN, 64, 0, stream>>>(x1, idx, Wv[1], bv[1], hmax, hmin, sumP, sqP);
  bn_finalize<<<1, 256, 0, stream>>>(sumP, sqP, gv[1], bev[1], scale, shift, 64, invMk);
  bn_apply_max<<<(BN * 64 + 255) / 256, 256, 0, stream>>>(hmax, hmin, scale, shift, x2, 63,
                                                          BN * 64);

  // ---- block 3: C=64 -> D=64 ----
  knn_kernel<64><<<BN, 256, 0, stream>>>(x2, idx);
  hipMemsetAsync(sumP, 0, NPART * 64 * 8, stream);
  hipMemsetAsync(sqP, 0, NPART * 64 * 8, stream);
  edgeconv<64, 64><<<BN, 64, 0, stream>>>(x2, idx, Wv[2], bv[2], hmax, hmin, sumP, sqP);
  bn_finalize<<<1, 256, 0, stream>>>(sumP, sqP, gv[2], bev[2], scale, shift, 64, invMk);
  bn_apply_max<<<(BN * 64 + 255) / 256, 256, 0, stream>>>(hmax, hmin, scale, shift, x3, 63,
                                                          BN * 64);

  // ---- block 4: C=64 -> D=128 ----
  knn_kernel<64><<<BN, 256, 0, stream>>>(x3, idx);
  hipMemsetAsync(sumP, 0, NPART * 128 * 8, stream);
  hipMemsetAsync(sqP, 0, NPART * 128 * 8, stream);
  edgeconv<64, 128><<<BN, 128, 0, stream>>>(x3, idx, Wv[3], bv[3], hmax, hmin, sumP, sqP);
  bn_finalize<<<1, 256, 0, stream>>>(sumP, sqP, gv[3], bev[3], scale, shift, 128, invMk);
  bn_apply_max<<<(BN * 128 + 255) / 256, 256, 0, stream>>>(hmax, hmin, scale, shift, x4, 127,
                                                           BN * 128);

  // ---- final: [BN,320] @ [320,1024], max over n ----
  hipMemsetAsync(sumP, 0, NPART * 1024 * 8, stream);
  hipMemsetAsync(sqP, 0, NPART * 1024 * 8, stream);
  hipMemsetAsync(h5max, 0, B * 1024 * 4, stream);
  hipMemsetAsync(h5min, 0x7f, B * 1024 * 4, stream);
  final_gemm<<<BN, 256, 0, stream>>>(x1, x2, x3, x4, Wv[4], bv[4], h5max, h5min, sumP, sqP);
  bn_finalize<<<4, 256, 0, stream>>>(sumP, sqP, gv[4], bev[4], scale, shift, 1024,
                                     1.0 / (double)BN);
  final_apply<<<(B * 1024 + 255) / 256, 256, 0, stream>>>(h5max, h5min, scale, shift,
                                                          (float*)d_out);
}

// Round 3
// 2908.896 us; speedup vs baseline: 2.5213x; 2.5213x over previous
//
#include <hip/hip_runtime.h>
#include <stdint.h>

namespace {

constexpr int B = 8, N = 2048, KNN = 20;
constexpr int NPART = 64;

// x [B][3][N] -> feat0 [B*N][3]
__global__ void transpose_x(const float* __restrict__ x, float* __restrict__ f) {
  int i = blockIdx.x * 256 + threadIdx.x;
  if (i >= B * N * 3) return;
  int c = i % 3, n = (i / 3) % N, b = i / (3 * N);
  f[i] = x[((size_t)b * 3 + c) * N + n];
}

// [B][N][64] -> [B][64][N], 32x32 LDS tiles
__global__ void transpose64(const float* __restrict__ in, float* __restrict__ out) {
  __shared__ float t[32][33];
  int b = blockIdx.z;
  int n0 = blockIdx.x * 32, c0 = blockIdx.y * 32;
  const float* ib = in + (size_t)b * N * 64;
  float* ob = out + (size_t)b * 64 * N;
  int tx = threadIdx.x & 31, ty = threadIdx.x >> 5;  // 32 x 8
#pragma unroll
  for (int i = 0; i < 32; i += 8) t[ty + i][tx] = ib[(size_t)(n0 + ty + i) * 64 + c0 + tx];
  __syncthreads();
#pragma unroll
  for (int i = 0; i < 32; i += 8) ob[(size_t)(c0 + ty + i) * N + n0 + tx] = t[tx][ty + i];
}

// fp64 squared norms, row-major [BN][64] input; one wave per point
__global__ void sqnorm64(const float* __restrict__ x, double* __restrict__ sqd) {
  int bn = blockIdx.x * 4 + (threadIdx.x >> 6);
  int lane = threadIdx.x & 63;
  double v = (double)x[(size_t)bn * 64 + lane];
  double s = v * v;
#pragma unroll
  for (int off = 32; off; off >>= 1) s += __shfl_xor(s, off, 64);
  if (lane == 0) sqd[bn] = s;
}

// fp64 squared norms from x [B][3][N]
__global__ void sqnorm3(const float* __restrict__ x, double* __restrict__ sqd) {
  int i = blockIdx.x * 256 + threadIdx.x;
  if (i >= B * N) return;
  int b = i >> 11, n = i & (N - 1);
  const float* xb = x + (size_t)b * 3 * N;
  double s = 0.0;
#pragma unroll
  for (int c = 0; c < 3; c++) {
    double v = (double)xb[(size_t)c * N + n];
    s += v * v;
  }
  sqd[i] = s;
}

// kNN: 4 queries per block (one per wave at selection). Distances via fp64
// expand formula d_cmp[m] = sqm[m] - 2*dot(q,m)  (query norm constant dropped:
// doesn't affect ordering). Selection: lexicographic (val, idx) extraction,
// 20 iters, register-resident, no rescans of LDS.
template <int C>
__global__ void __launch_bounds__(256) knn_kernel(const float* __restrict__ featT,
                                                  const double* __restrict__ sqd,
                                                  int* __restrict__ idx20) {
  __shared__ double dist[4][N];  // 64 KB; first bytes double as fq storage
  float* fqs = (float*)&dist[0][0];
  int t = threadIdx.x;
  int qb = blockIdx.x * 4;
  int b = qb >> 11;
  const float* fT = featT + (size_t)b * C * N;
  if (t < 4 * C) {
    int w = t / C, c = t % C;
    fqs[t] = fT[(size_t)c * N + ((qb + w) & (N - 1))];
  }
  __syncthreads();
  double acc[4][8];
#pragma unroll
  for (int q = 0; q < 4; q++)
#pragma unroll
    for (int j = 0; j < 8; j++) acc[q][j] = 0.0;
  for (int c = 0; c < C; c++) {
    float v[8];
#pragma unroll
    for (int j = 0; j < 8; j++) v[j] = fT[(size_t)c * N + t + 256 * j];
    double f0 = (double)fqs[0 * C + c], f1 = (double)fqs[1 * C + c];
    double f2 = (double)fqs[2 * C + c], f3 = (double)fqs[3 * C + c];
#pragma unroll
    for (int j = 0; j < 8; j++) {
      double vd = (double)v[j];
      acc[0][j] = fma(vd, f0, acc[0][j]);
      acc[1][j] = fma(vd, f1, acc[1][j]);
      acc[2][j] = fma(vd, f2, acc[2][j]);
      acc[3][j] = fma(vd, f3, acc[3][j]);
    }
  }
  __syncthreads();  // all fq reads done before overwriting LDS with dist
#pragma unroll
  for (int j = 0; j < 8; j++) {
    double sm = sqd[(size_t)b * N + t + 256 * j];
#pragma unroll
    for (int q = 0; q < 4; q++) dist[q][t + 256 * j] = fma(-2.0, acc[q][j], sm);
  }
  __syncthreads();
  int w = t >> 6, lane = t & 63;
  double d[32];
#pragma unroll
  for (int j = 0; j < 32; j++) d[j] = dist[w][j * 64 + lane];
  double gv = -1.0e300;
  int gi = -1;
  int* op = idx20 + (size_t)(qb + w) * KNN;
  for (int it = 0; it < KNN; it++) {
    double bv = 1.0e300;
    int bi = 0x7fffffff;
#pragma unroll
    for (int j = 0; j < 32; j++) {
      int mi = j * 64 + lane;
      bool after = (d[j] > gv) || (d[j] == gv && mi > gi);
      if (after && d[j] < bv) { bv = d[j]; bi = mi; }
    }
#pragma unroll
    for (int s = 1; s < 64; s <<= 1) {
      double ov = __shfl_xor(bv, s, 64);
      int oi = __shfl_xor(bi, s, 64);
      if (ov < bv || (ov == bv && oi < bi)) { bv = ov; bi = oi; }
    }
    gv = bv;
    gi = bi;
    if (lane == 0) op[it] = bi;
  }
}

// EdgeConv factorization: u' = A*(Wt - Wb) + bias, v = A*Wb.
// A: [BN][K] row-major. W: [2K][D]. One block = 64-row tile.
template <int K, int D>
__global__ void __launch_bounds__(256) gemm_uv(const float* __restrict__ A,
                                               const float* __restrict__ W,
                                               const float* __restrict__ bias,
                                               float* __restrict__ u, float* __restrict__ v) {
  constexpr int RG = 256 / D;   // row groups
  constexpr int RPT = 64 / RG;  // rows per thread
  __shared__ float At[64][K];
  int t = threadIdx.x;
  int n0 = blockIdx.x * 64;
  for (int i = t; i < 64 * K; i += 256) At[i / K][i % K] = A[(size_t)n0 * K + i];
  __syncthreads();
  int col = t & (D - 1), rg = t / D;
  float au[RPT], av[RPT];
  float bb = bias[col];
#pragma unroll
  for (int r = 0; r < RPT; r++) {
    au[r] = bb;
    av[r] = 0.f;
  }
  for (int c = 0; c < K; c++) {
    float wt = W[(size_t)c * D + col];
    float wb = W[(size_t)(K + c) * D + col];
    float wu = wt - wb;
#pragma unroll
    for (int r = 0; r < RPT; r++) {
      float a = At[rg * RPT + r][c];
      au[r] = fmaf(a, wu, au[r]);
      av[r] = fmaf(a, wb, av[r]);
    }
  }
#pragma unroll
  for (int r = 0; r < RPT; r++) {
    u[(size_t)(n0 + rg * RPT + r) * D + col] = au[r];
    v[(size_t)(n0 + rg * RPT + r) * D + col] = av[r];
  }
}

// h[n,j,d] = relu(u'[n,d] + v[idx[n,j],d]); track max/min over j + fp64 stats.
template <int D>
__global__ void __launch_bounds__(256) combine_max(const float* __restrict__ u,
                                                   const float* __restrict__ v,
                                                   const int* __restrict__ idx20,
                                                   float* __restrict__ hmax,
                                                   float* __restrict__ hmin,
                                                   double* __restrict__ sumP,
                                                   double* __restrict__ sqP) {
  constexpr int PPB = 256 / D;
  int t = threadIdx.x;
  int p = t / D, d = t & (D - 1);
  int bn = blockIdx.x * PPB + p;
  int b = bn >> 11;
  const int* ip = idx20 + (size_t)bn * KNN;
  float up = u[(size_t)bn * D + d];
  const float* vb = v + ((size_t)b << 11) * D;
  float mx = -1e30f, mn = 1e30f;
  double s = 0.0, q = 0.0;
#pragma unroll 4
  for (int j = 0; j < KNN; j++) {
    int nb = ip[j];
    float hv = up + vb[(size_t)nb * D + d];
    hv = hv > 0.f ? hv : 0.f;
    mx = fmaxf(mx, hv);
    mn = fminf(mn, hv);
    double hd = (double)hv;
    s += hd;
    q = fma(hd, hd, q);
  }
  hmax[(size_t)bn * D + d] = mx;
  hmin[(size_t)bn * D + d] = mn;
  int slot = bn & (NPART - 1);
  atomicAdd(&sumP[(size_t)slot * D + d], s);
  atomicAdd(&sqP[(size_t)slot * D + d], q);
}

__global__ void bn_finalize(const double* __restrict__ sumP, const double* __restrict__ sqP,
                            const float* __restrict__ g, const float* __restrict__ be,
                            float* __restrict__ scale, float* __restrict__ shift, int D,
                            double invM) {
  int d = blockIdx.x * 256 + threadIdx.x;
  if (d >= D) return;
  double s = 0.0, q = 0.0;
  for (int i = 0; i < NPART; i++) {
    s += sumP[i * D + d];
    q += sqP[i * D + d];
  }
  double mean = s * invM;
  double var = q * invM - mean * mean;
  double sc = (double)g[d] / sqrt(var + 1e-5);
  scale[d] = (float)sc;
  shift[d] = (float)((double)be[d] - mean * sc);
}

__global__ void bn_apply_max(const float* __restrict__ hmax, const float* __restrict__ hmin,
                             const float* __restrict__ scale, const float* __restrict__ shift,
                             float* __restrict__ out, int dmask, int total) {
  int i = blockIdx.x * 256 + threadIdx.x;
  if (i >= total) return;
  int d = i & dmask;
  float sc = scale[d];
  float v = sc >= 0.f ? hmax[i] : hmin[i];
  out[i] = v * sc + shift[d];
}

// [16384,320]x[320,1024]: 32-row x 256-col tiles; per-thread max/min/stats
// over its 32 rows (all same batch), one atomic set per thread.
__global__ void __launch_bounds__(256) final_gemm(const float* __restrict__ x1,
                                                  const float* __restrict__ x2,
                                                  const float* __restrict__ x3,
                                                  const float* __restrict__ x4,
                                                  const float* __restrict__ W5,
                                                  const float* __restrict__ b5,
                                                  unsigned int* __restrict__ h5max,
                                                  unsigned int* __restrict__ h5min,
                                                  double* __restrict__ sumP,
                                                  double* __restrict__ sqP) {
  __shared__ float At[32][320];  // 40 KB
  int t = threadIdx.x;
  int n0 = (blockIdx.x >> 2) * 32;
  int col = ((blockIdx.x & 3) << 8) + t;
  for (int i = t; i < 32 * 320; i += 256) {
    int r = i / 320, c = i % 320;
    int n = n0 + r;
    float vv;
    if (c < 64) vv = x1[(size_t)n * 64 + c];
    else if (c < 128) vv = x2[(size_t)n * 64 + c - 64];
    else if (c < 192) vv = x3[(size_t)n * 64 + c - 128];
    else vv = x4[(size_t)n * 128 + c - 192];
    At[r][c] = vv;
  }
  __syncthreads();
  float acc[32];
  float bb = b5[col];
#pragma unroll
  for (int r = 0; r < 32; r++) acc[r] = bb;
  for (int c = 0; c < 320; c++) {
    float w = W5[(size_t)c * 1024 + col];
#pragma unroll
    for (int r = 0; r < 32; r++) acc[r] = fmaf(At[r][c], w, acc[r]);
  }
  int b = n0 >> 11;
  float mx = -1e30f, mn = 1e30f;
  double s = 0.0, q = 0.0;
#pragma unroll
  for (int r = 0; r < 32; r++) {
    float hv = acc[r] > 0.f ? acc[r] : 0.f;
    mx = fmaxf(mx, hv);
    mn = fminf(mn, hv);
    double hd = (double)hv;
    s += hd;
    q = fma(hd, hd, q);
  }
  atomicMax(&h5max[(size_t)b * 1024 + col], __float_as_uint(mx));
  atomicMin(&h5min[(size_t)b * 1024 + col], __float_as_uint(mn));
  int slot = blockIdx.x & (NPART - 1);
  atomicAdd(&sumP[(size_t)slot * 1024 + col], s);
  atomicAdd(&sqP[(size_t)slot * 1024 + col], q);
}

__global__ void final_apply(const unsigned int* __restrict__ h5max,
                            const unsigned int* __restrict__ h5min,
                            const float* __restrict__ scale, const float* __restrict__ shift,
                            float* __restrict__ out) {
  int i = blockIdx.x * 256 + threadIdx.x;
  if (i >= B * 1024) return;
  int ch = i & 1023;
  float sc = scale[ch];
  float v = __uint_as_float(sc >= 0.f ? h5max[i] : h5min[i]);
  out[i] = v * sc + shift[ch];
}

}  // namespace

extern "C" void kernel_launch(void* const* d_in, const int* in_sizes, int n_in,
                              void* d_out, int out_size, void* d_ws, size_t ws_size,
                              hipStream_t stream) {
  const float* x = (const float*)d_in[0];
  const float *Wv[5], *bv[5], *gv[5], *bev[5];
  for (int i = 0; i < 5; i++) {
    Wv[i] = (const float*)d_in[1 + 4 * i];
    bv[i] = (const float*)d_in[2 + 4 * i];
    gv[i] = (const float*)d_in[3 + 4 * i];
    bev[i] = (const float*)d_in[4 + 4 * i];
  }

  char* ws = (char*)d_ws;
  size_t off = 0;
  auto alloc = [&](size_t bytes) {
    size_t r = off;
    off = (off + bytes + 255) & ~(size_t)255;
    return r;
  };
  const int BN = B * N;
  float* feat0 = (float*)(ws + alloc((size_t)BN * 3 * 4));
  int* idx = (int*)(ws + alloc((size_t)BN * KNN * 4));
  float* x1 = (float*)(ws + alloc((size_t)BN * 64 * 4));
  float* x2 = (float*)(ws + alloc((size_t)BN * 64 * 4));
  float* x3 = (float*)(ws + alloc((size_t)BN * 64 * 4));
  float* x4 = (float*)(ws + alloc((size_t)BN * 128 * 4));
  float* xT = (float*)(ws + alloc((size_t)BN * 64 * 4));
  float* ub = (float*)(ws + alloc((size_t)BN * 128 * 4));
  float* vb = (float*)(ws + alloc((size_t)BN * 128 * 4));
  float* hmax = (float*)(ws + alloc((size_t)BN * 128 * 4));
  float* hmin = (float*)(ws + alloc((size_t)BN * 128 * 4));
  double* sqd = (double*)(ws + alloc((size_t)BN * 8));
  double* sumP = (double*)(ws + alloc((size_t)NPART * 1024 * 8));
  double* sqP = (double*)(ws + alloc((size_t)NPART * 1024 * 8));
  float* scale = (float*)(ws + alloc(1024 * 4));
  float* shift = (float*)(ws + alloc(1024 * 4));
  unsigned int* h5max = (unsigned int*)(ws + alloc((size_t)B * 1024 * 4));
  unsigned int* h5min = (unsigned int*)(ws + alloc((size_t)B * 1024 * 4));

  const double invMk = 1.0 / ((double)BN * KNN);
  dim3 tgrid(N / 32, 64 / 32, B);

  transpose_x<<<(BN * 3 + 255) / 256, 256, 0, stream>>>(x, feat0);

  // ---- layer 1: C=3 -> D=64 (x is already [B][3][N] == transposed) ----
  sqnorm3<<<(BN + 255) / 256, 256, 0, stream>>>(x, sqd);
  knn_kernel<3><<<BN / 4, 256, 0, stream>>>(x, sqd, idx);
  gemm_uv<3, 64><<<BN / 64, 256, 0, stream>>>(feat0, Wv[0], bv[0], ub, vb);
  hipMemsetAsync(sumP, 0, NPART * 64 * 8, stream);
  hipMemsetAsync(sqP, 0, NPART * 64 * 8, stream);
  combine_max<64><<<BN / 4, 256, 0, stream>>>(ub, vb, idx, hmax, hmin, sumP, sqP);
  bn_finalize<<<1, 256, 0, stream>>>(sumP, sqP, gv[0], bev[0], scale, shift, 64, invMk);
  bn_apply_max<<<(BN * 64 + 255) / 256, 256, 0, stream>>>(hmax, hmin, scale, shift, x1, 63,
                                                          BN * 64);

  // ---- layer 2: C=64 -> D=64 ----
  transpose64<<<tgrid, 256, 0, stream>>>(x1, xT);
  sqnorm64<<<BN / 4, 256, 0, stream>>>(x1, sqd);
  knn_kernel<64><<<BN / 4, 256, 0, stream>>>(xT, sqd, idx);
  gemm_uv<64, 64><<<BN / 64, 256, 0, stream>>>(x1, Wv[1], bv[1], ub, vb);
  hipMemsetAsync(sumP, 0, NPART * 64 * 8, stream);
  hipMemsetAsync(sqP, 0, NPART * 64 * 8, stream);
  combine_max<64><<<BN / 4, 256, 0, stream>>>(ub, vb, idx, hmax, hmin, sumP, sqP);
  bn_finalize<<<1, 256, 0, stream>>>(sumP, sqP, gv[1], bev[1], scale, shift, 64, invMk);
  bn_apply_max<<<(BN * 64 + 255) / 256, 256, 0, stream>>>(hmax, hmin, scale, shift, x2, 63,
                                                          BN * 64);

  // ---- layer 3: C=64 -> D=64 ----
  transpose64<<<tgrid, 256, 0, stream>>>(x2, xT);
  sqnorm64<<<BN / 4, 256, 0, stream>>>(x2, sqd);
  knn_kernel<64><<<BN / 4, 256, 0, stream>>>(xT, sqd, idx);
  gemm_uv<64, 64><<<BN / 64, 256, 0, stream>>>(x2, Wv[2], bv[2], ub, vb);
  hipMemsetAsync(sumP, 0, NPART * 64 * 8, stream);
  hipMemsetAsync(sqP, 0, NPART * 64 * 8, stream);
  combine_max<64><<<BN / 4, 256, 0, stream>>>(ub, vb, idx, hmax, hmin, sumP, sqP);
  bn_finalize<<<1, 256, 0, stream>>>(sumP, sqP, gv[2], bev[2], scale, shift, 64, invMk);
  bn_apply_max<<<(BN * 64 + 255) / 256, 256, 0, stream>>>(hmax, hmin, scale, shift, x3, 63,
                                                          BN * 64);

  // ---- layer 4: C=64 -> D=128 ----
  transpose64<<<tgrid, 256, 0, stream>>>(x3, xT);
  sqnorm64<<<BN / 4, 256, 0, stream>>>(x3, sqd);
  knn_kernel<64><<<BN / 4, 256, 0, stream>>>(xT, sqd, idx);
  gemm_uv<64, 128><<<BN / 64, 256, 0, stream>>>(x3, Wv[3], bv[3], ub, vb);
  hipMemsetAsync(sumP, 0, NPART * 128 * 8, stream);
  hipMemsetAsync(sqP, 0, NPART * 128 * 8, stream);
  combine_max<128><<<BN / 2, 256, 0, stream>>>(ub, vb, idx, hmax, hmin, sumP, sqP);
  bn_finalize<<<1, 256, 0, stream>>>(sumP, sqP, gv[3], bev[3], scale, shift, 128, invMk);
  bn_apply_max<<<(BN * 128 + 255) / 256, 256, 0, stream>>>(hmax, hmin, scale, shift, x4, 127,
                                                           BN * 128);

  // ---- final: [BN,320] @ [320,1024], max over n ----
  hipMemsetAsync(sumP, 0, NPART * 1024 * 8, stream);
  hipMemsetAsync(sqP, 0, NPART * 1024 * 8, stream);
  hipMemsetAsync(h5max, 0, B * 1024 * 4, stream);
  hipMemsetAsync(h5min, 0x7f, B * 1024 * 4, stream);
  final_gemm<<<(BN / 32) * 4, 256, 0, stream>>>(x1, x2, x3, x4, Wv[4], bv[4], h5max, h5min,
                                                sumP, sqP);
  bn_finalize<<<4, 256, 0, stream>>>(sumP, sqP, gv[4], bev[4], scale, shift, 1024,
                                     1.0 / (double)BN);
  final_apply<<<(B * 1024 + 255) / 256, 256, 0, stream>>>(h5max, h5min, scale, shift,
                                                          (float*)d_out);
}

// Round 4
// 1891.901 us; speedup vs baseline: 3.8766x; 1.5376x over previous
//
#include <hip/hip_runtime.h>
#include <stdint.h>

namespace {

constexpr int B = 8, N = 2048, KNN = 20;
constexpr int NPART = 64;

// x [B][3][N] -> feat0 [B*N][3]
__global__ void transpose_x(const float* __restrict__ x, float* __restrict__ f) {
  int i = blockIdx.x * 256 + threadIdx.x;
  if (i >= B * N * 3) return;
  int c = i % 3, n = (i / 3) % N, b = i / (3 * N);
  f[i] = x[((size_t)b * 3 + c) * N + n];
}

// [B][N][64] -> [B][64][N], 32x32 LDS tiles
__global__ void transpose64(const float* __restrict__ in, float* __restrict__ out) {
  __shared__ float t[32][33];
  int b = blockIdx.z;
  int n0 = blockIdx.x * 32, c0 = blockIdx.y * 32;
  const float* ib = in + (size_t)b * N * 64;
  float* ob = out + (size_t)b * 64 * N;
  int tx = threadIdx.x & 31, ty = threadIdx.x >> 5;  // 32 x 8
#pragma unroll
  for (int i = 0; i < 32; i += 8) t[ty + i][tx] = ib[(size_t)(n0 + ty + i) * 64 + c0 + tx];
  __syncthreads();
#pragma unroll
  for (int i = 0; i < 32; i += 8) ob[(size_t)(c0 + ty + i) * N + n0 + tx] = t[tx][ty + i];
}

// fp32 squared norms from row-major [BN][64]
__global__ void sqnormf_row(const float* __restrict__ x, float* __restrict__ sqf) {
  int bn = blockIdx.x * 4 + (threadIdx.x >> 6);
  int lane = threadIdx.x & 63;
  float v = x[(size_t)bn * 64 + lane];
  float s = v * v;
#pragma unroll
  for (int off = 32; off; off >>= 1) s += __shfl_xor(s, off, 64);
  if (lane == 0) sqf[bn] = s;
}

// fp32 squared norms from x [B][3][N]
__global__ void sqnormf3(const float* __restrict__ x, float* __restrict__ sqf) {
  int i = blockIdx.x * 256 + threadIdx.x;
  if (i >= B * N) return;
  int b = i >> 11, n = i & (N - 1);
  const float* xb = x + (size_t)b * 3 * N;
  float s = 0.f;
#pragma unroll
  for (int c = 0; c < 3; c++) {
    float v = xb[(size_t)c * N + n];
    s = fmaf(v, v, s);
  }
  sqf[i] = s;
}

// fp32 candidate selection + fp64 exact refine for one query.
// A[32] holds dot(q, point) on entry for points  pt(k) = (k>>2)*256 + lane*4 + (k&3).
template <int C>
__device__ __forceinline__ void select_refine(float (&A)[32], int lane, int qloc,
                                              const float* __restrict__ sqb,
                                              const float* __restrict__ rowB,
                                              const float (*qfeat)[C], int (*candBuf)[64],
                                              int* __restrict__ op) {
  // dot -> comparison distance d = |m|^2 - 2*dot (query-norm constant dropped)
  const float4* sq4 = (const float4*)sqb;
#pragma unroll
  for (int j8 = 0; j8 < 8; j8++) {
    float4 sv = sq4[j8 * 64 + lane];
    A[4 * j8 + 0] = fmaf(-2.f, A[4 * j8 + 0], sv.x);
    A[4 * j8 + 1] = fmaf(-2.f, A[4 * j8 + 1], sv.y);
    A[4 * j8 + 2] = fmaf(-2.f, A[4 * j8 + 2], sv.z);
    A[4 * j8 + 3] = fmaf(-2.f, A[4 * j8 + 3], sv.w);
  }
  // per-lane branchless sorted top-8 (ascending)
  float s[8];
#pragma unroll
  for (int i = 0; i < 8; i++) s[i] = 1e30f;
#pragma unroll
  for (int k = 0; k < 32; k++) {
    float t0 = A[k];
#pragma unroll
    for (int i = 0; i < 8; i++) {
      float lo = fminf(s[i], t0);
      t0 = fmaxf(s[i], t0);
      s[i] = lo;
    }
  }
  // 32 wave-min pops -> threshold T at rank >= 32
  float T = 0.f;
  for (int it = 0; it < 32; it++) {
    float m = s[0];
#pragma unroll
    for (int off = 1; off < 64; off <<= 1) m = fminf(m, __shfl_xor(m, off, 64));
    bool win = (s[0] == m);
#pragma unroll
    for (int i = 0; i < 7; i++) s[i] = win ? s[i + 1] : s[i];
    s[7] = win ? 1e30f : s[7];
    T = m;
  }
  // ballot-compact candidates (d <= T) into LDS
  int base = 0;
#pragma unroll
  for (int k = 0; k < 32; k++) {
    bool p = (A[k] <= T);
    unsigned long long mk = __ballot(p);
    if (p) {
      int pos = base + (int)__popcll(mk & ((1ull << lane) - 1));
      if (pos < 64) candBuf[qloc][pos] = (k >> 2) * 256 + lane * 4 + (k & 3);
    }
    base += (int)__popcll(mk);
  }
  int cnt = base < 64 ? base : 64;
  // fp64 exact distance for my candidate (difference formula)
  int mc = (lane < cnt) ? candBuf[qloc][lane] : 0;
  double dd = 0.0;
  if constexpr (C % 4 == 0) {
    const float4* r4 = (const float4*)(rowB + (size_t)mc * C);
    const float4* q4 = (const float4*)(&qfeat[qloc][0]);
#pragma unroll 4
    for (int k = 0; k < C / 4; k++) {
      float4 rv = r4[k];
      float4 qv = q4[k];
      double d0 = (double)qv.x - (double)rv.x;
      dd = fma(d0, d0, dd);
      double d1 = (double)qv.y - (double)rv.y;
      dd = fma(d1, d1, dd);
      double d2 = (double)qv.z - (double)rv.z;
      dd = fma(d2, d2, dd);
      double d3 = (double)qv.w - (double)rv.w;
      dd = fma(d3, d3, dd);
    }
  } else {
    const float* r = rowB + (size_t)mc * C;
#pragma unroll
    for (int c = 0; c < C; c++) {
      double d0 = (double)qfeat[qloc][c] - (double)r[c];
      dd = fma(d0, d0, dd);
    }
  }
  int myi = (lane < cnt) ? mc : 0x7fffffff;
  if (lane >= cnt) dd = 1e300;
  // top-20 extraction, (d, idx) lexicographic
  for (int it = 0; it < KNN; it++) {
    double bv = dd;
    int bi = myi;
#pragma unroll
    for (int off = 1; off < 64; off <<= 1) {
      double ov = __shfl_xor(bv, off, 64);
      int oi = __shfl_xor(bi, off, 64);
      if (ov < bv || (ov == bv && oi < bi)) {
        bv = ov;
        bi = oi;
      }
    }
    if (lane == 0) op[it] = bi;
    if (myi == bi) dd = 1e300;
  }
}

// 8 queries per 256-thread block; each wave owns 2 queries.
template <int C>
__global__ void __launch_bounds__(256) knn_fused(const float* __restrict__ fT,
                                                 const float* __restrict__ rowF,
                                                 const float* __restrict__ sqf,
                                                 int* __restrict__ idx20) {
  __shared__ __align__(16) float qfeat[8][C];
  __shared__ int candBuf[8][64];
  int t = threadIdx.x, w = t >> 6, lane = t & 63;
  int q0 = blockIdx.x * 8;  // global bn of first query (same batch for all 8)
  int b = q0 >> 11;
  for (int i = t; i < 8 * C; i += 256) qfeat[i / C][i % C] = rowF[(size_t)q0 * C + i];
  __syncthreads();
  const float* fTb = fT + (size_t)b * C * N;
  const float* rowB = rowF + (((size_t)b) << 11) * C;
  const float* sqb = sqf + (((size_t)b) << 11);
  int qa = w * 2, qbl = w * 2 + 1;
  float acc0[32], acc1[32];
#pragma unroll
  for (int j = 0; j < 32; j++) {
    acc0[j] = 0.f;
    acc1[j] = 0.f;
  }
  for (int c = 0; c < C; c++) {
    float qc0 = qfeat[qa][c], qc1 = qfeat[qbl][c];
    const float4* r4 = (const float4*)(fTb + (size_t)c * N);
#pragma unroll
    for (int j8 = 0; j8 < 8; j8++) {
      float4 v = r4[j8 * 64 + lane];
      acc0[4 * j8 + 0] = fmaf(v.x, qc0, acc0[4 * j8 + 0]);
      acc0[4 * j8 + 1] = fmaf(v.y, qc0, acc0[4 * j8 + 1]);
      acc0[4 * j8 + 2] = fmaf(v.z, qc0, acc0[4 * j8 + 2]);
      acc0[4 * j8 + 3] = fmaf(v.w, qc0, acc0[4 * j8 + 3]);
      acc1[4 * j8 + 0] = fmaf(v.x, qc1, acc1[4 * j8 + 0]);
      acc1[4 * j8 + 1] = fmaf(v.y, qc1, acc1[4 * j8 + 1]);
      acc1[4 * j8 + 2] = fmaf(v.z, qc1, acc1[4 * j8 + 2]);
      acc1[4 * j8 + 3] = fmaf(v.w, qc1, acc1[4 * j8 + 3]);
    }
  }
  select_refine<C>(acc0, lane, qa, sqb, rowB, qfeat, candBuf, idx20 + (size_t)(q0 + qa) * KNN);
  select_refine<C>(acc1, lane, qbl, sqb, rowB, qfeat, candBuf, idx20 + (size_t)(q0 + qbl) * KNN);
}

// EdgeConv factorization: u' = A*(Wt - Wb) + bias, v = A*Wb.
template <int K, int D>
__global__ void __launch_bounds__(256) gemm_uv(const float* __restrict__ A,
                                               const float* __restrict__ W,
                                               const float* __restrict__ bias,
                                               float* __restrict__ u, float* __restrict__ v) {
  constexpr int RG = 256 / D;
  constexpr int RPT = 64 / RG;
  __shared__ float At[64][K];
  int t = threadIdx.x;
  int n0 = blockIdx.x * 64;
  for (int i = t; i < 64 * K; i += 256) At[i / K][i % K] = A[(size_t)n0 * K + i];
  __syncthreads();
  int col = t & (D - 1), rg = t / D;
  float au[RPT], av[RPT];
  float bb = bias[col];
#pragma unroll
  for (int r = 0; r < RPT; r++) {
    au[r] = bb;
    av[r] = 0.f;
  }
  for (int c = 0; c < K; c++) {
    float wt = W[(size_t)c * D + col];
    float wb = W[(size_t)(K + c) * D + col];
    float wu = wt - wb;
#pragma unroll
    for (int r = 0; r < RPT; r++) {
      float a = At[rg * RPT + r][c];
      au[r] = fmaf(a, wu, au[r]);
      av[r] = fmaf(a, wb, av[r]);
    }
  }
#pragma unroll
  for (int r = 0; r < RPT; r++) {
    u[(size_t)(n0 + rg * RPT + r) * D + col] = au[r];
    v[(size_t)(n0 + rg * RPT + r) * D + col] = av[r];
  }
}

// h[n,j,d] = relu(u'[n,d] + v[idx[n,j],d]); max/min over j + fp64 stats.
template <int D>
__global__ void __launch_bounds__(256) combine_max(const float* __restrict__ u,
                                                   const float* __restrict__ v,
                                                   const int* __restrict__ idx20,
                                                   float* __restrict__ hmax,
                                                   float* __restrict__ hmin,
                                                   double* __restrict__ sumP,
                                                   double* __restrict__ sqP) {
  constexpr int PPB = 256 / D;
  int t = threadIdx.x;
  int p = t / D, d = t & (D - 1);
  int bn = blockIdx.x * PPB + p;
  int b = bn >> 11;
  const int* ip = idx20 + (size_t)bn * KNN;
  float up = u[(size_t)bn * D + d];
  const float* vb = v + ((size_t)b << 11) * D;
  float mx = -1e30f, mn = 1e30f;
  double s = 0.0, q = 0.0;
#pragma unroll 4
  for (int j = 0; j < KNN; j++) {
    int nb = ip[j];
    float hv = up + vb[(size_t)nb * D + d];
    hv = hv > 0.f ? hv : 0.f;
    mx = fmaxf(mx, hv);
    mn = fminf(mn, hv);
    double hd = (double)hv;
    s += hd;
    q = fma(hd, hd, q);
  }
  hmax[(size_t)bn * D + d] = mx;
  hmin[(size_t)bn * D + d] = mn;
  int slot = bn & (NPART - 1);
  atomicAdd(&sumP[(size_t)slot * D + d], s);
  atomicAdd(&sqP[(size_t)slot * D + d], q);
}

__global__ void bn_finalize(const double* __restrict__ sumP, const double* __restrict__ sqP,
                            const float* __restrict__ g, const float* __restrict__ be,
                            float* __restrict__ scale, float* __restrict__ shift, int D,
                            double invM) {
  int d = blockIdx.x * 256 + threadIdx.x;
  if (d >= D) return;
  double s = 0.0, q = 0.0;
  for (int i = 0; i < NPART; i++) {
    s += sumP[i * D + d];
    q += sqP[i * D + d];
  }
  double mean = s * invM;
  double var = q * invM - mean * mean;
  double sc = (double)g[d] / sqrt(var + 1e-5);
  scale[d] = (float)sc;
  shift[d] = (float)((double)be[d] - mean * sc);
}

__global__ void bn_apply_max(const float* __restrict__ hmax, const float* __restrict__ hmin,
                             const float* __restrict__ scale, const float* __restrict__ shift,
                             float* __restrict__ out, int dmask, int total) {
  int i = blockIdx.x * 256 + threadIdx.x;
  if (i >= total) return;
  int d = i & dmask;
  float sc = scale[d];
  float v = sc >= 0.f ? hmax[i] : hmin[i];
  out[i] = v * sc + shift[d];
}

// [16384,320]x[320,1024]: 32-row x 256-col tiles.
__global__ void __launch_bounds__(256) final_gemm(const float* __restrict__ x1,
                                                  const float* __restrict__ x2,
                                                  const float* __restrict__ x3,
                                                  const float* __restrict__ x4,
                                                  const float* __restrict__ W5,
                                                  const float* __restrict__ b5,
                                                  unsigned int* __restrict__ h5max,
                                                  unsigned int* __restrict__ h5min,
                                                  double* __restrict__ sumP,
                                                  double* __restrict__ sqP) {
  __shared__ float At[32][320];
  int t = threadIdx.x;
  int n0 = (blockIdx.x >> 2) * 32;
  int col = ((blockIdx.x & 3) << 8) + t;
  for (int i = t; i < 32 * 320; i += 256) {
    int r = i / 320, c = i % 320;
    int n = n0 + r;
    float vv;
    if (c < 64) vv = x1[(size_t)n * 64 + c];
    else if (c < 128) vv = x2[(size_t)n * 64 + c - 64];
    else if (c < 192) vv = x3[(size_t)n * 64 + c - 128];
    else vv = x4[(size_t)n * 128 + c - 192];
    At[r][c] = vv;
  }
  __syncthreads();
  float acc[32];
  float bb = b5[col];
#pragma unroll
  for (int r = 0; r < 32; r++) acc[r] = bb;
  for (int c = 0; c < 320; c++) {
    float w = W5[(size_t)c * 1024 + col];
#pragma unroll
    for (int r = 0; r < 32; r++) acc[r] = fmaf(At[r][c], w, acc[r]);
  }
  int b = n0 >> 11;
  float mx = -1e30f, mn = 1e30f;
  double s = 0.0, q = 0.0;
#pragma unroll
  for (int r = 0; r < 32; r++) {
    float hv = acc[r] > 0.f ? acc[r] : 0.f;
    mx = fmaxf(mx, hv);
    mn = fminf(mn, hv);
    double hd = (double)hv;
    s += hd;
    q = fma(hd, hd, q);
  }
  atomicMax(&h5max[(size_t)b * 1024 + col], __float_as_uint(mx));
  atomicMin(&h5min[(size_t)b * 1024 + col], __float_as_uint(mn));
  int slot = blockIdx.x & (NPART - 1);
  atomicAdd(&sumP[(size_t)slot * 1024 + col], s);
  atomicAdd(&sqP[(size_t)slot * 1024 + col], q);
}

__global__ void final_apply(const unsigned int* __restrict__ h5max,
                            const unsigned int* __restrict__ h5min,
                            const float* __restrict__ scale, const float* __restrict__ shift,
                            float* __restrict__ out) {
  int i = blockIdx.x * 256 + threadIdx.x;
  if (i >= B * 1024) return;
  int ch = i & 1023;
  float sc = scale[ch];
  float v = __uint_as_float(sc >= 0.f ? h5max[i] : h5min[i]);
  out[i] = v * sc + shift[ch];
}

}  // namespace

extern "C" void kernel_launch(void* const* d_in, const int* in_sizes, int n_in,
                              void* d_out, int out_size, void* d_ws, size_t ws_size,
                              hipStream_t stream) {
  const float* x = (const float*)d_in[0];
  const float *Wv[5], *bv[5], *gv[5], *bev[5];
  for (int i = 0; i < 5; i++) {
    Wv[i] = (const float*)d_in[1 + 4 * i];
    bv[i] = (const float*)d_in[2 + 4 * i];
    gv[i] = (const float*)d_in[3 + 4 * i];
    bev[i] = (const float*)d_in[4 + 4 * i];
  }

  char* ws = (char*)d_ws;
  size_t off = 0;
  auto alloc = [&](size_t bytes) {
    size_t r = off;
    off = (off + bytes + 255) & ~(size_t)255;
    return r;
  };
  const int BN = B * N;
  float* feat0 = (float*)(ws + alloc((size_t)BN * 3 * 4));
  int* idx = (int*)(ws + alloc((size_t)BN * KNN * 4));
  float* x1 = (float*)(ws + alloc((size_t)BN * 64 * 4));
  float* x2 = (float*)(ws + alloc((size_t)BN * 64 * 4));
  float* x3 = (float*)(ws + alloc((size_t)BN * 64 * 4));
  float* x4 = (float*)(ws + alloc((size_t)BN * 128 * 4));
  float* xT = (float*)(ws + alloc((size_t)BN * 64 * 4));
  float* ub = (float*)(ws + alloc((size_t)BN * 128 * 4));
  float* vb = (float*)(ws + alloc((size_t)BN * 128 * 4));
  float* hmax = (float*)(ws + alloc((size_t)BN * 128 * 4));
  float* hmin = (float*)(ws + alloc((size_t)BN * 128 * 4));
  float* sqf = (float*)(ws + alloc((size_t)BN * 4));
  double* sumP = (double*)(ws + alloc((size_t)NPART * 1024 * 8));
  double* sqP = (double*)(ws + alloc((size_t)NPART * 1024 * 8));
  float* scale = (float*)(ws + alloc(1024 * 4));
  float* shift = (float*)(ws + alloc(1024 * 4));
  unsigned int* h5max = (unsigned int*)(ws + alloc((size_t)B * 1024 * 4));
  unsigned int* h5min = (unsigned int*)(ws + alloc((size_t)B * 1024 * 4));

  const double invMk = 1.0 / ((double)BN * KNN);
  dim3 tgrid(N / 32, 64 / 32, B);

  transpose_x<<<(BN * 3 + 255) / 256, 256, 0, stream>>>(x, feat0);

  // ---- layer 1: C=3 -> D=64 (x is already [B][3][N]) ----
  sqnormf3<<<(BN + 255) / 256, 256, 0, stream>>>(x, sqf);
  knn_fused<3><<<BN / 8, 256, 0, stream>>>(x, feat0, sqf, idx);
  gemm_uv<3, 64><<<BN / 64, 256, 0, stream>>>(feat0, Wv[0], bv[0], ub, vb);
  hipMemsetAsync(sumP, 0, NPART * 64 * 8, stream);
  hipMemsetAsync(sqP, 0, NPART * 64 * 8, stream);
  combine_max<64><<<BN / 4, 256, 0, stream>>>(ub, vb, idx, hmax, hmin, sumP, sqP);
  bn_finalize<<<1, 256, 0, stream>>>(sumP, sqP, gv[0], bev[0], scale, shift, 64, invMk);
  bn_apply_max<<<(BN * 64 + 255) / 256, 256, 0, stream>>>(hmax, hmin, scale, shift, x1, 63,
                                                          BN * 64);

  // ---- layer 2: C=64 -> D=64 ----
  transpose64<<<tgrid, 256, 0, stream>>>(x1, xT);
  sqnormf_row<<<BN / 4, 256, 0, stream>>>(x1, sqf);
  knn_fused<64><<<BN / 8, 256, 0, stream>>>(xT, x1, sqf, idx);
  gemm_uv<64, 64><<<BN / 64, 256, 0, stream>>>(x1, Wv[1], bv[1], ub, vb);
  hipMemsetAsync(sumP, 0, NPART * 64 * 8, stream);
  hipMemsetAsync(sqP, 0, NPART * 64 * 8, stream);
  combine_max<64><<<BN / 4, 256, 0, stream>>>(ub, vb, idx, hmax, hmin, sumP, sqP);
  bn_finalize<<<1, 256, 0, stream>>>(sumP, sqP, gv[1], bev[1], scale, shift, 64, invMk);
  bn_apply_max<<<(BN * 64 + 255) / 256, 256, 0, stream>>>(hmax, hmin, scale, shift, x2, 63,
                                                          BN * 64);

  // ---- layer 3: C=64 -> D=64 ----
  transpose64<<<tgrid, 256, 0, stream>>>(x2, xT);
  sqnormf_row<<<BN / 4, 256, 0, stream>>>(x2, sqf);
  knn_fused<64><<<BN / 8, 256, 0, stream>>>(xT, x2, sqf, idx);
  gemm_uv<64, 64><<<BN / 64, 256, 0, stream>>>(x2, Wv[2], bv[2], ub, vb);
  hipMemsetAsync(sumP, 0, NPART * 64 * 8, stream);
  hipMemsetAsync(sqP, 0, NPART * 64 * 8, stream);
  combine_max<64><<<BN / 4, 256, 0, stream>>>(ub, vb, idx, hmax, hmin, sumP, sqP);
  bn_finalize<<<1, 256, 0, stream>>>(sumP, sqP, gv[2], bev[2], scale, shift, 64, invMk);
  bn_apply_max<<<(BN * 64 + 255) / 256, 256, 0, stream>>>(hmax, hmin, scale, shift, x3, 63,
                                                          BN * 64);

  // ---- layer 4: C=64 -> D=128 ----
  transpose64<<<tgrid, 256, 0, stream>>>(x3, xT);
  sqnormf_row<<<BN / 4, 256, 0, stream>>>(x3, sqf);
  knn_fused<64><<<BN / 8, 256, 0, stream>>>(xT, x3, sqf, idx);
  gemm_uv<64, 128><<<BN / 64, 256, 0, stream>>>(x3, Wv[3], bv[3], ub, vb);
  hipMemsetAsync(sumP, 0, NPART * 128 * 8, stream);
  hipMemsetAsync(sqP, 0, NPART * 128 * 8, stream);
  combine_max<128><<<BN / 2, 256, 0, stream>>>(ub, vb, idx, hmax, hmin, sumP, sqP);
  bn_finalize<<<1, 256, 0, stream>>>(sumP, sqP, gv[3], bev[3], scale, shift, 128, invMk);
  bn_apply_max<<<(BN * 128 + 255) / 256, 256, 0, stream>>>(hmax, hmin, scale, shift, x4, 127,
                                                           BN * 128);

  // ---- final: [BN,320] @ [320,1024], max over n ----
  hipMemsetAsync(sumP, 0, NPART * 1024 * 8, stream);
  hipMemsetAsync(sqP, 0, NPART * 1024 * 8, stream);
  hipMemsetAsync(h5max, 0, B * 1024 * 4, stream);
  hipMemsetAsync(h5min, 0x7f, B * 1024 * 4, stream);
  final_gemm<<<(BN / 32) * 4, 256, 0, stream>>>(x1, x2, x3, x4, Wv[4], bv[4], h5max, h5min,
                                                sumP, sqP);
  bn_finalize<<<4, 256, 0, stream>>>(sumP, sqP, gv[4], bev[4], scale, shift, 1024,
                                     1.0 / (double)BN);
  final_apply<<<(B * 1024 + 255) / 256, 256, 0, stream>>>(h5max, h5min, scale, shift,
                                                          (float*)d_out);
}

// Round 5
// 1221.565 us; speedup vs baseline: 6.0038x; 1.5488x over previous
//
#include <hip/hip_runtime.h>
#include <stdint.h>

namespace {

constexpr int B = 8, N = 2048, KNN = 20;
constexpr int NPART = 64;

// x [B][3][N] -> feat0 [B*N][3]
__global__ void transpose_x(const float* __restrict__ x, float* __restrict__ f) {
  int i = blockIdx.x * 256 + threadIdx.x;
  if (i >= B * N * 3) return;
  int c = i % 3, n = (i / 3) % N, b = i / (3 * N);
  f[i] = x[((size_t)b * 3 + c) * N + n];
}

// [B][N][64] -> [B][64][N], 32x32 LDS tiles
__global__ void transpose64(const float* __restrict__ in, float* __restrict__ out) {
  __shared__ float t[32][33];
  int b = blockIdx.z;
  int n0 = blockIdx.x * 32, c0 = blockIdx.y * 32;
  const float* ib = in + (size_t)b * N * 64;
  float* ob = out + (size_t)b * 64 * N;
  int tx = threadIdx.x & 31, ty = threadIdx.x >> 5;  // 32 x 8
#pragma unroll
  for (int i = 0; i < 32; i += 8) t[ty + i][tx] = ib[(size_t)(n0 + ty + i) * 64 + c0 + tx];
  __syncthreads();
#pragma unroll
  for (int i = 0; i < 32; i += 8) ob[(size_t)(c0 + ty + i) * N + n0 + tx] = t[tx][ty + i];
}

// fp32 squared norms from row-major [BN][64]
__global__ void sqnormf_row(const float* __restrict__ x, float* __restrict__ sqf) {
  int bn = blockIdx.x * 4 + (threadIdx.x >> 6);
  int lane = threadIdx.x & 63;
  float v = x[(size_t)bn * 64 + lane];
  float s = v * v;
#pragma unroll
  for (int off = 32; off; off >>= 1) s += __shfl_xor(s, off, 64);
  if (lane == 0) sqf[bn] = s;
}

// fp32 squared norms from x [B][3][N]
__global__ void sqnormf3(const float* __restrict__ x, float* __restrict__ sqf) {
  int i = blockIdx.x * 256 + threadIdx.x;
  if (i >= B * N) return;
  int b = i >> 11, n = i & (N - 1);
  const float* xb = x + (size_t)b * 3 * N;
  float s = 0.f;
#pragma unroll
  for (int c = 0; c < 3; c++) {
    float v = xb[(size_t)c * N + n];
    s = fmaf(v, v, s);
  }
  sqf[i] = s;
}

// fp32 candidate selection + fp64 exact refine for one query.
// A[32] holds dot(q, point) on entry for points  pt(k) = (k>>2)*256 + lane*4 + (k&3).
template <int C>
__device__ __forceinline__ void select_refine(float (&A)[32], int lane, int qloc,
                                              const float* __restrict__ sqb,
                                              const float* __restrict__ rowB,
                                              const float (*qfeat)[C], int (*candBuf)[64],
                                              int* __restrict__ op) {
  // dot -> comparison distance d = |m|^2 - 2*dot (query-norm constant dropped)
  const float4* sq4 = (const float4*)sqb;
#pragma unroll
  for (int j8 = 0; j8 < 8; j8++) {
    float4 sv = sq4[j8 * 64 + lane];
    A[4 * j8 + 0] = fmaf(-2.f, A[4 * j8 + 0], sv.x);
    A[4 * j8 + 1] = fmaf(-2.f, A[4 * j8 + 1], sv.y);
    A[4 * j8 + 2] = fmaf(-2.f, A[4 * j8 + 2], sv.z);
    A[4 * j8 + 3] = fmaf(-2.f, A[4 * j8 + 3], sv.w);
  }
  // per-lane branchless sorted top-8 (ascending)
  float s[8];
#pragma unroll
  for (int i = 0; i < 8; i++) s[i] = 1e30f;
#pragma unroll
  for (int k = 0; k < 32; k++) {
    float t0 = A[k];
#pragma unroll
    for (int i = 0; i < 8; i++) {
      float lo = fminf(s[i], t0);
      t0 = fmaxf(s[i], t0);
      s[i] = lo;
    }
  }
  // 32 wave-min pops -> threshold T at rank >= 32
  float T = 0.f;
  for (int it = 0; it < 32; it++) {
    float m = s[0];
#pragma unroll
    for (int off = 1; off < 64; off <<= 1) m = fminf(m, __shfl_xor(m, off, 64));
    bool win = (s[0] == m);
#pragma unroll
    for (int i = 0; i < 7; i++) s[i] = win ? s[i + 1] : s[i];
    s[7] = win ? 1e30f : s[7];
    T = m;
  }
  // ballot-compact candidates (d <= T) into LDS
  int base = 0;
#pragma unroll
  for (int k = 0; k < 32; k++) {
    bool p = (A[k] <= T);
    unsigned long long mk = __ballot(p);
    if (p) {
      int pos = base + (int)__popcll(mk & ((1ull << lane) - 1));
      if (pos < 64) candBuf[qloc][pos] = (k >> 2) * 256 + lane * 4 + (k & 3);
    }
    base += (int)__popcll(mk);
  }
  int cnt = base < 64 ? base : 64;
  // fp64 exact distance for my candidate (difference formula)
  int mc = (lane < cnt) ? candBuf[qloc][lane] : 0;
  double dd = 0.0;
  if constexpr (C % 4 == 0) {
    const float4* r4 = (const float4*)(rowB + (size_t)mc * C);
    const float4* q4 = (const float4*)(&qfeat[qloc][0]);
#pragma unroll 4
    for (int k = 0; k < C / 4; k++) {
      float4 rv = r4[k];
      float4 qv = q4[k];
      double d0 = (double)qv.x - (double)rv.x;
      dd = fma(d0, d0, dd);
      double d1 = (double)qv.y - (double)rv.y;
      dd = fma(d1, d1, dd);
      double d2 = (double)qv.z - (double)rv.z;
      dd = fma(d2, d2, dd);
      double d3 = (double)qv.w - (double)rv.w;
      dd = fma(d3, d3, dd);
    }
  } else {
    const float* r = rowB + (size_t)mc * C;
#pragma unroll
    for (int c = 0; c < C; c++) {
      double d0 = (double)qfeat[qloc][c] - (double)r[c];
      dd = fma(d0, d0, dd);
    }
  }
  int myi = (lane < cnt) ? mc : 0x7fffffff;
  if (lane >= cnt) dd = 1e300;
  // bitonic sort of 64 (dd, myi) pairs ascending; lanes 0..19 hold the top-20
#pragma unroll
  for (int k = 2; k <= 64; k <<= 1) {
#pragma unroll
    for (int j = k >> 1; j > 0; j >>= 1) {
      double od = __shfl_xor(dd, j, 64);
      int oi = __shfl_xor(myi, j, 64);
      bool up = (lane & k) == 0;
      bool lower = (lane & j) == 0;
      bool cmp = (od < dd) || (od == dd && oi < myi);  // other strictly smaller
      bool take = (up == lower) ? cmp : !cmp;
      if (take) {
        dd = od;
        myi = oi;
      }
    }
  }
  if (lane < KNN) op[lane] = myi;
}

// C=3: 8 queries per 256-thread block; each wave owns 2 queries; direct global reads.
template <int C>
__global__ void __launch_bounds__(256) knn_fused(const float* __restrict__ fT,
                                                 const float* __restrict__ rowF,
                                                 const float* __restrict__ sqf,
                                                 int* __restrict__ idx20) {
  __shared__ __align__(16) float qfeat[8][C];
  __shared__ int candBuf[8][64];
  int t = threadIdx.x, w = t >> 6, lane = t & 63;
  int q0 = blockIdx.x * 8;
  int b = q0 >> 11;
  for (int i = t; i < 8 * C; i += 256) qfeat[i / C][i % C] = rowF[(size_t)q0 * C + i];
  __syncthreads();
  const float* fTb = fT + (size_t)b * C * N;
  const float* rowB = rowF + (((size_t)b) << 11) * C;
  const float* sqb = sqf + (((size_t)b) << 11);
  int qa = w * 2, qbl = w * 2 + 1;
  float acc0[32], acc1[32];
#pragma unroll
  for (int j = 0; j < 32; j++) {
    acc0[j] = 0.f;
    acc1[j] = 0.f;
  }
  for (int c = 0; c < C; c++) {
    float qc0 = qfeat[qa][c], qc1 = qfeat[qbl][c];
    const float4* r4 = (const float4*)(fTb + (size_t)c * N);
#pragma unroll
    for (int j8 = 0; j8 < 8; j8++) {
      float4 v = r4[j8 * 64 + lane];
      acc0[4 * j8 + 0] = fmaf(v.x, qc0, acc0[4 * j8 + 0]);
      acc0[4 * j8 + 1] = fmaf(v.y, qc0, acc0[4 * j8 + 1]);
      acc0[4 * j8 + 2] = fmaf(v.z, qc0, acc0[4 * j8 + 2]);
      acc0[4 * j8 + 3] = fmaf(v.w, qc0, acc0[4 * j8 + 3]);
      acc1[4 * j8 + 0] = fmaf(v.x, qc1, acc1[4 * j8 + 0]);
      acc1[4 * j8 + 1] = fmaf(v.y, qc1, acc1[4 * j8 + 1]);
      acc1[4 * j8 + 2] = fmaf(v.z, qc1, acc1[4 * j8 + 2]);
      acc1[4 * j8 + 3] = fmaf(v.w, qc1, acc1[4 * j8 + 3]);
    }
  }
  select_refine<C>(acc0, lane, qa, sqb, rowB, qfeat, candBuf, idx20 + (size_t)(q0 + qa) * KNN);
  select_refine<C>(acc1, lane, qbl, sqb, rowB, qfeat, candBuf, idx20 + (size_t)(q0 + qbl) * KNN);
}

// C=64: LDS-staged dot phase. Block stages 2 channels x 2048 pts (16 KB) double-buffered;
// all 4 waves compute from LDS -> global feature traffic 512KB/block instead of 2MB.
__global__ void __launch_bounds__(256) knn_fused64(const float* __restrict__ fT,
                                                   const float* __restrict__ rowF,
                                                   const float* __restrict__ sqf,
                                                   int* __restrict__ idx20) {
  __shared__ __align__(16) float stage[2][2 * N];  // 32 KB
  __shared__ __align__(16) float qfeat[8][64];     // 2 KB
  __shared__ int candBuf[8][64];                   // 2 KB
  int t = threadIdx.x, w = t >> 6, lane = t & 63;
  int q0 = blockIdx.x * 8;
  int b = q0 >> 11;
  const float* fTb = fT + (size_t)b * 64 * N;
  const float4* src4 = (const float4*)fTb;  // row c = f4 [c*512 .. c*512+511]
  for (int i = t; i < 8 * 64; i += 256) qfeat[i >> 6][i & 63] = rowF[(size_t)q0 * 64 + i];

  // prologue: stage chunk 0 (channels 0,1)
  float4 st[4];
#pragma unroll
  for (int p = 0; p < 4; p++) st[p] = src4[t + 256 * p];
  {
    float4* d4 = (float4*)&stage[0][0];
#pragma unroll
    for (int p = 0; p < 4; p++) d4[t + 256 * p] = st[p];
  }
  __syncthreads();

  int qa = w * 2, qbl = w * 2 + 1;
  float acc0[32], acc1[32];
#pragma unroll
  for (int j = 0; j < 32; j++) {
    acc0[j] = 0.f;
    acc1[j] = 0.f;
  }

  for (int chunk = 0; chunk < 32; chunk++) {
    int cur = chunk & 1;
    if (chunk < 31) {  // issue next chunk's loads early (T14)
#pragma unroll
      for (int p = 0; p < 4; p++) st[p] = src4[(chunk + 1) * 1024 + t + 256 * p];
    }
#pragma unroll
    for (int cc = 0; cc < 2; cc++) {
      int c = chunk * 2 + cc;
      float qc0 = qfeat[qa][c], qc1 = qfeat[qbl][c];
      const float4* r4 = (const float4*)&stage[cur][cc * N];
#pragma unroll
      for (int j8 = 0; j8 < 8; j8++) {
        float4 v = r4[j8 * 64 + lane];
        acc0[4 * j8 + 0] = fmaf(v.x, qc0, acc0[4 * j8 + 0]);
        acc0[4 * j8 + 1] = fmaf(v.y, qc0, acc0[4 * j8 + 1]);
        acc0[4 * j8 + 2] = fmaf(v.z, qc0, acc0[4 * j8 + 2]);
        acc0[4 * j8 + 3] = fmaf(v.w, qc0, acc0[4 * j8 + 3]);
        acc1[4 * j8 + 0] = fmaf(v.x, qc1, acc1[4 * j8 + 0]);
        acc1[4 * j8 + 1] = fmaf(v.y, qc1, acc1[4 * j8 + 1]);
        acc1[4 * j8 + 2] = fmaf(v.z, qc1, acc1[4 * j8 + 2]);
        acc1[4 * j8 + 3] = fmaf(v.w, qc1, acc1[4 * j8 + 3]);
      }
    }
    if (chunk < 31) {  // write-late into the other buffer
      float4* d4 = (float4*)&stage[cur ^ 1][0];
#pragma unroll
      for (int p = 0; p < 4; p++) d4[t + 256 * p] = st[p];
    }
    __syncthreads();
  }
  const float* rowB = rowF + (((size_t)b) << 11) * 64;
  const float* sqb = sqf + (((size_t)b) << 11);
  select_refine<64>(acc0, lane, qa, sqb, rowB, qfeat, candBuf, idx20 + (size_t)(q0 + qa) * KNN);
  select_refine<64>(acc1, lane, qbl, sqb, rowB, qfeat, candBuf,
                    idx20 + (size_t)(q0 + qbl) * KNN);
}

// EdgeConv factorization: u' = A*(Wt - Wb) + bias, v = A*Wb.
template <int K, int D>
__global__ void __launch_bounds__(256) gemm_uv(const float* __restrict__ A,
                                               const float* __restrict__ W,
                                               const float* __restrict__ bias,
                                               float* __restrict__ u, float* __restrict__ v) {
  constexpr int RG = 256 / D;
  constexpr int RPT = 64 / RG;
  __shared__ float At[64][K];
  int t = threadIdx.x;
  int n0 = blockIdx.x * 64;
  for (int i = t; i < 64 * K; i += 256) At[i / K][i % K] = A[(size_t)n0 * K + i];
  __syncthreads();
  int col = t & (D - 1), rg = t / D;
  float au[RPT], av[RPT];
  float bb = bias[col];
#pragma unroll
  for (int r = 0; r < RPT; r++) {
    au[r] = bb;
    av[r] = 0.f;
  }
  for (int c = 0; c < K; c++) {
    float wt = W[(size_t)c * D + col];
    float wb = W[(size_t)(K + c) * D + col];
    float wu = wt - wb;
#pragma unroll
    for (int r = 0; r < RPT; r++) {
      float a = At[rg * RPT + r][c];
      au[r] = fmaf(a, wu, au[r]);
      av[r] = fmaf(a, wb, av[r]);
    }
  }
#pragma unroll
  for (int r = 0; r < RPT; r++) {
    u[(size_t)(n0 + rg * RPT + r) * D + col] = au[r];
    v[(size_t)(n0 + rg * RPT + r) * D + col] = av[r];
  }
}

// h[n,j,d] = relu(u'[n,d] + v[idx[n,j],d]); max/min over j + fp64 stats.
template <int D>
__global__ void __launch_bounds__(256) combine_max(const float* __restrict__ u,
                                                   const float* __restrict__ v,
                                                   const int* __restrict__ idx20,
                                                   float* __restrict__ hmax,
                                                   float* __restrict__ hmin,
                                                   double* __restrict__ sumP,
                                                   double* __restrict__ sqP) {
  constexpr int PPB = 256 / D;
  int t = threadIdx.x;
  int p = t / D, d = t & (D - 1);
  int bn = blockIdx.x * PPB + p;
  int b = bn >> 11;
  const int* ip = idx20 + (size_t)bn * KNN;
  float up = u[(size_t)bn * D + d];
  const float* vb = v + ((size_t)b << 11) * D;
  float mx = -1e30f, mn = 1e30f;
  double s = 0.0, q = 0.0;
#pragma unroll 4
  for (int j = 0; j < KNN; j++) {
    int nb = ip[j];
    float hv = up + vb[(size_t)nb * D + d];
    hv = hv > 0.f ? hv : 0.f;
    mx = fmaxf(mx, hv);
    mn = fminf(mn, hv);
    double hd = (double)hv;
    s += hd;
    q = fma(hd, hd, q);
  }
  hmax[(size_t)bn * D + d] = mx;
  hmin[(size_t)bn * D + d] = mn;
  int slot = bn & (NPART - 1);
  atomicAdd(&sumP[(size_t)slot * D + d], s);
  atomicAdd(&sqP[(size_t)slot * D + d], q);
}

__global__ void bn_finalize(const double* __restrict__ sumP, const double* __restrict__ sqP,
                            const float* __restrict__ g, const float* __restrict__ be,
                            float* __restrict__ scale, float* __restrict__ shift, int D,
                            double invM) {
  int d = blockIdx.x * 256 + threadIdx.x;
  if (d >= D) return;
  double s = 0.0, q = 0.0;
  for (int i = 0; i < NPART; i++) {
    s += sumP[i * D + d];
    q += sqP[i * D + d];
  }
  double mean = s * invM;
  double var = q * invM - mean * mean;
  double sc = (double)g[d] / sqrt(var + 1e-5);
  scale[d] = (float)sc;
  shift[d] = (float)((double)be[d] - mean * sc);
}

__global__ void bn_apply_max(const float* __restrict__ hmax, const float* __restrict__ hmin,
                             const float* __restrict__ scale, const float* __restrict__ shift,
                             float* __restrict__ out, int dmask, int total) {
  int i = blockIdx.x * 256 + threadIdx.x;
  if (i >= total) return;
  int d = i & dmask;
  float sc = scale[d];
  float v = sc >= 0.f ? hmax[i] : hmin[i];
  out[i] = v * sc + shift[d];
}

// [16384,320]x[320,1024]: 32-row x 256-col tiles.
__global__ void __launch_bounds__(256) final_gemm(const float* __restrict__ x1,
                                                  const float* __restrict__ x2,
                                                  const float* __restrict__ x3,
                                                  const float* __restrict__ x4,
                                                  const float* __restrict__ W5,
                                                  const float* __restrict__ b5,
                                                  unsigned int* __restrict__ h5max,
                                                  unsigned int* __restrict__ h5min,
                                                  double* __restrict__ sumP,
                                                  double* __restrict__ sqP) {
  __shared__ float At[32][320];
  int t = threadIdx.x;
  int n0 = (blockIdx.x >> 2) * 32;
  int col = ((blockIdx.x & 3) << 8) + t;
  for (int i = t; i < 32 * 320; i += 256) {
    int r = i / 320, c = i % 320;
    int n = n0 + r;
    float vv;
    if (c < 64) vv = x1[(size_t)n * 64 + c];
    else if (c < 128) vv = x2[(size_t)n * 64 + c - 64];
    else if (c < 192) vv = x3[(size_t)n * 64 + c - 128];
    else vv = x4[(size_t)n * 128 + c - 192];
    At[r][c] = vv;
  }
  __syncthreads();
  float acc[32];
  float bb = b5[col];
#pragma unroll
  for (int r = 0; r < 32; r++) acc[r] = bb;
  for (int c = 0; c < 320; c++) {
    float w = W5[(size_t)c * 1024 + col];
#pragma unroll
    for (int r = 0; r < 32; r++) acc[r] = fmaf(At[r][c], w, acc[r]);
  }
  int b = n0 >> 11;
  float mx = -1e30f, mn = 1e30f;
  double s = 0.0, q = 0.0;
#pragma unroll
  for (int r = 0; r < 32; r++) {
    float hv = acc[r] > 0.f ? acc[r] : 0.f;
    mx = fmaxf(mx, hv);
    mn = fminf(mn, hv);
    double hd = (double)hv;
    s += hd;
    q = fma(hd, hd, q);
  }
  atomicMax(&h5max[(size_t)b * 1024 + col], __float_as_uint(mx));
  atomicMin(&h5min[(size_t)b * 1024 + col], __float_as_uint(mn));
  int slot = blockIdx.x & (NPART - 1);
  atomicAdd(&sumP[(size_t)slot * 1024 + col], s);
  atomicAdd(&sqP[(size_t)slot * 1024 + col], q);
}

__global__ void final_apply(const unsigned int* __restrict__ h5max,
                            const unsigned int* __restrict__ h5min,
                            const float* __restrict__ scale, const float* __restrict__ shift,
                            float* __restrict__ out) {
  int i = blockIdx.x * 256 + threadIdx.x;
  if (i >= B * 1024) return;
  int ch = i & 1023;
  float sc = scale[ch];
  float v = __uint_as_float(sc >= 0.f ? h5max[i] : h5min[i]);
  out[i] = v * sc + shift[ch];
}

}  // namespace

extern "C" void kernel_launch(void* const* d_in, const int* in_sizes, int n_in,
                              void* d_out, int out_size, void* d_ws, size_t ws_size,
                              hipStream_t stream) {
  const float* x = (const float*)d_in[0];
  const float *Wv[5], *bv[5], *gv[5], *bev[5];
  for (int i = 0; i < 5; i++) {
    Wv[i] = (const float*)d_in[1 + 4 * i];
    bv[i] = (const float*)d_in[2 + 4 * i];
    gv[i] = (const float*)d_in[3 + 4 * i];
    bev[i] = (const float*)d_in[4 + 4 * i];
  }

  char* ws = (char*)d_ws;
  size_t off = 0;
  auto alloc = [&](size_t bytes) {
    size_t r = off;
    off = (off + bytes + 255) & ~(size_t)255;
    return r;
  };
  const int BN = B * N;
  float* feat0 = (float*)(ws + alloc((size_t)BN * 3 * 4));
  int* idx = (int*)(ws + alloc((size_t)BN * KNN * 4));
  float* x1 = (float*)(ws + alloc((size_t)BN * 64 * 4));
  float* x2 = (float*)(ws + alloc((size_t)BN * 64 * 4));
  float* x3 = (float*)(ws + alloc((size_t)BN * 64 * 4));
  float* x4 = (float*)(ws + alloc((size_t)BN * 128 * 4));
  float* xT = (float*)(ws + alloc((size_t)BN * 64 * 4));
  float* ub = (float*)(ws + alloc((size_t)BN * 128 * 4));
  float* vb = (float*)(ws + alloc((size_t)BN * 128 * 4));
  float* hmax = (float*)(ws + alloc((size_t)BN * 128 * 4));
  float* hmin = (float*)(ws + alloc((size_t)BN * 128 * 4));
  float* sqf = (float*)(ws + alloc((size_t)BN * 4));
  double* sumP = (double*)(ws + alloc((size_t)NPART * 1024 * 8));
  double* sqP = (double*)(ws + alloc((size_t)NPART * 1024 * 8));
  float* scale = (float*)(ws + alloc(1024 * 4));
  float* shift = (float*)(ws + alloc(1024 * 4));
  unsigned int* h5max = (unsigned int*)(ws + alloc((size_t)B * 1024 * 4));
  unsigned int* h5min = (unsigned int*)(ws + alloc((size_t)B * 1024 * 4));

  const double invMk = 1.0 / ((double)BN * KNN);
  dim3 tgrid(N / 32, 64 / 32, B);

  transpose_x<<<(BN * 3 + 255) / 256, 256, 0, stream>>>(x, feat0);

  // ---- layer 1: C=3 -> D=64 (x is already [B][3][N]) ----
  sqnormf3<<<(BN + 255) / 256, 256, 0, stream>>>(x, sqf);
  knn_fused<3><<<BN / 8, 256, 0, stream>>>(x, feat0, sqf, idx);
  gemm_uv<3, 64><<<BN / 64, 256, 0, stream>>>(feat0, Wv[0], bv[0], ub, vb);
  hipMemsetAsync(sumP, 0, NPART * 64 * 8, stream);
  hipMemsetAsync(sqP, 0, NPART * 64 * 8, stream);
  combine_max<64><<<BN / 4, 256, 0, stream>>>(ub, vb, idx, hmax, hmin, sumP, sqP);
  bn_finalize<<<1, 256, 0, stream>>>(sumP, sqP, gv[0], bev[0], scale, shift, 64, invMk);
  bn_apply_max<<<(BN * 64 + 255) / 256, 256, 0, stream>>>(hmax, hmin, scale, shift, x1, 63,
                                                          BN * 64);

  // ---- layer 2: C=64 -> D=64 ----
  transpose64<<<tgrid, 256, 0, stream>>>(x1, xT);
  sqnormf_row<<<BN / 4, 256, 0, stream>>>(x1, sqf);
  knn_fused64<<<BN / 8, 256, 0, stream>>>(xT, x1, sqf, idx);
  gemm_uv<64, 64><<<BN / 64, 256, 0, stream>>>(x1, Wv[1], bv[1], ub, vb);
  hipMemsetAsync(sumP, 0, NPART * 64 * 8, stream);
  hipMemsetAsync(sqP, 0, NPART * 64 * 8, stream);
  combine_max<64><<<BN / 4, 256, 0, stream>>>(ub, vb, idx, hmax, hmin, sumP, sqP);
  bn_finalize<<<1, 256, 0, stream>>>(sumP, sqP, gv[1], bev[1], scale, shift, 64, invMk);
  bn_apply_max<<<(BN * 64 + 255) / 256, 256, 0, stream>>>(hmax, hmin, scale, shift, x2, 63,
                                                          BN * 64);

  // ---- layer 3: C=64 -> D=64 ----
  transpose64<<<tgrid, 256, 0, stream>>>(x2, xT);
  sqnormf_row<<<BN / 4, 256, 0, stream>>>(x2, sqf);
  knn_fused64<<<BN / 8, 256, 0, stream>>>(xT, x2, sqf, idx);
  gemm_uv<64, 64><<<BN / 64, 256, 0, stream>>>(x2, Wv[2], bv[2], ub, vb);
  hipMemsetAsync(sumP, 0, NPART * 64 * 8, stream);
  hipMemsetAsync(sqP, 0, NPART * 64 * 8, stream);
  combine_max<64><<<BN / 4, 256, 0, stream>>>(ub, vb, idx, hmax, hmin, sumP, sqP);
  bn_finalize<<<1, 256, 0, stream>>>(sumP, sqP, gv[2], bev[2], scale, shift, 64, invMk);
  bn_apply_max<<<(BN * 64 + 255) / 256, 256, 0, stream>>>(hmax, hmin, scale, shift, x3, 63,
                                                          BN * 64);

  // ---- layer 4: C=64 -> D=128 ----
  transpose64<<<tgrid, 256, 0, stream>>>(x3, xT);
  sqnormf_row<<<BN / 4, 256, 0, stream>>>(x3, sqf);
  knn_fused64<<<BN / 8, 256, 0, stream>>>(xT, x3, sqf, idx);
  gemm_uv<64, 128><<<BN / 64, 256, 0, stream>>>(x3, Wv[3], bv[3], ub, vb);
  hipMemsetAsync(sumP, 0, NPART * 128 * 8, stream);
  hipMemsetAsync(sqP, 0, NPART * 128 * 8, stream);
  combine_max<128><<<BN / 2, 256, 0, stream>>>(ub, vb, idx, hmax, hmin, sumP, sqP);
  bn_finalize<<<1, 256, 0, stream>>>(sumP, sqP, gv[3], bev[3], scale, shift, 128, invMk);
  bn_apply_max<<<(BN * 128 + 255) / 256, 256, 0, stream>>>(hmax, hmin, scale, shift, x4, 127,
                                                           BN * 128);

  // ---- final: [BN,320] @ [320,1024], max over n ----
  hipMemsetAsync(sumP, 0, NPART * 1024 * 8, stream);
  hipMemsetAsync(sqP, 0, NPART * 1024 * 8, stream);
  hipMemsetAsync(h5max, 0, B * 1024 * 4, stream);
  hipMemsetAsync(h5min, 0x7f, B * 1024 * 4, stream);
  final_gemm<<<(BN / 32) * 4, 256, 0, stream>>>(x1, x2, x3, x4, Wv[4], bv[4], h5max, h5min,
                                                sumP, sqP);
  bn_finalize<<<4, 256, 0, stream>>>(sumP, sqP, gv[4], bev[4], scale, shift, 1024,
                                     1.0 / (double)BN);
  final_apply<<<(B * 1024 + 255) / 256, 256, 0, stream>>>(h5max, h5min, scale, shift,
                                                          (float*)d_out);
}

// Round 6
// 1089.630 us; speedup vs baseline: 6.7308x; 1.1211x over previous
//
#include <hip/hip_runtime.h>
#include <stdint.h>

namespace {

constexpr int B = 8, N = 2048, KNN = 20;
constexpr int NPART = 64;

// x [B][3][N] -> feat0 [B*N][3]
__global__ void transpose_x(const float* __restrict__ x, float* __restrict__ f) {
  int i = blockIdx.x * 256 + threadIdx.x;
  if (i >= B * N * 3) return;
  int c = i % 3, n = (i / 3) % N, b = i / (3 * N);
  f[i] = x[((size_t)b * 3 + c) * N + n];
}

// [B][N][64] -> [B][64][N], 32x32 LDS tiles
__global__ void transpose64(const float* __restrict__ in, float* __restrict__ out) {
  __shared__ float t[32][33];
  int b = blockIdx.z;
  int n0 = blockIdx.x * 32, c0 = blockIdx.y * 32;
  const float* ib = in + (size_t)b * N * 64;
  float* ob = out + (size_t)b * 64 * N;
  int tx = threadIdx.x & 31, ty = threadIdx.x >> 5;  // 32 x 8
#pragma unroll
  for (int i = 0; i < 32; i += 8) t[ty + i][tx] = ib[(size_t)(n0 + ty + i) * 64 + c0 + tx];
  __syncthreads();
#pragma unroll
  for (int i = 0; i < 32; i += 8) ob[(size_t)(c0 + ty + i) * N + n0 + tx] = t[tx][ty + i];
}

// fp32 squared norms from row-major [BN][64]
__global__ void sqnormf_row(const float* __restrict__ x, float* __restrict__ sqf) {
  int bn = blockIdx.x * 4 + (threadIdx.x >> 6);
  int lane = threadIdx.x & 63;
  float v = x[(size_t)bn * 64 + lane];
  float s = v * v;
#pragma unroll
  for (int off = 32; off; off >>= 1) s += __shfl_xor(s, off, 64);
  if (lane == 0) sqf[bn] = s;
}

// fp32 squared norms from x [B][3][N]
__global__ void sqnormf3(const float* __restrict__ x, float* __restrict__ sqf) {
  int i = blockIdx.x * 256 + threadIdx.x;
  if (i >= B * N) return;
  int b = i >> 11, n = i & (N - 1);
  const float* xb = x + (size_t)b * 3 * N;
  float s = 0.f;
#pragma unroll
  for (int c = 0; c < 3; c++) {
    float v = xb[(size_t)c * N + n];
    s = fmaf(v, v, s);
  }
  sqf[i] = s;
}

// fp32 candidate selection + fp64 exact refine for one query.
// A[32] holds dot(q, point) on entry for points  pt(k) = (k>>2)*256 + lane*4 + (k&3).
template <int C>
__device__ __forceinline__ void select_refine(float (&A)[32], int lane, int qloc,
                                              const float* __restrict__ sqb,
                                              const float* __restrict__ rowB,
                                              const float (*qfeat)[C], int (*candBuf)[64],
                                              int* __restrict__ op) {
  // dot -> comparison distance d = |m|^2 - 2*dot (query-norm constant dropped)
  const float4* sq4 = (const float4*)sqb;
#pragma unroll
  for (int j8 = 0; j8 < 8; j8++) {
    float4 sv = sq4[j8 * 64 + lane];
    A[4 * j8 + 0] = fmaf(-2.f, A[4 * j8 + 0], sv.x);
    A[4 * j8 + 1] = fmaf(-2.f, A[4 * j8 + 1], sv.y);
    A[4 * j8 + 2] = fmaf(-2.f, A[4 * j8 + 2], sv.z);
    A[4 * j8 + 3] = fmaf(-2.f, A[4 * j8 + 3], sv.w);
  }
  // per-lane branchless sorted top-8 (ascending)
  float s[8];
#pragma unroll
  for (int i = 0; i < 8; i++) s[i] = 1e30f;
#pragma unroll
  for (int k = 0; k < 32; k++) {
    float t0 = A[k];
#pragma unroll
    for (int i = 0; i < 8; i++) {
      float lo = fminf(s[i], t0);
      t0 = fmaxf(s[i], t0);
      s[i] = lo;
    }
  }
  // 32 wave-min pops -> threshold T at rank >= 32
  float T = 0.f;
  for (int it = 0; it < 32; it++) {
    float m = s[0];
#pragma unroll
    for (int off = 1; off < 64; off <<= 1) m = fminf(m, __shfl_xor(m, off, 64));
    bool win = (s[0] == m);
#pragma unroll
    for (int i = 0; i < 7; i++) s[i] = win ? s[i + 1] : s[i];
    s[7] = win ? 1e30f : s[7];
    T = m;
  }
  // ballot-compact candidates (d <= T) into LDS
  int base = 0;
#pragma unroll
  for (int k = 0; k < 32; k++) {
    bool p = (A[k] <= T);
    unsigned long long mk = __ballot(p);
    if (p) {
      int pos = base + (int)__popcll(mk & ((1ull << lane) - 1));
      if (pos < 64) candBuf[qloc][pos] = (k >> 2) * 256 + lane * 4 + (k & 3);
    }
    base += (int)__popcll(mk);
  }
  int cnt = base < 64 ? base : 64;
  // fp64 exact distance for my candidate (difference formula)
  int mc = (lane < cnt) ? candBuf[qloc][lane] : 0;
  double dd = 0.0;
  if constexpr (C % 4 == 0) {
    const float4* r4 = (const float4*)(rowB + (size_t)mc * C);
    const float4* q4 = (const float4*)(&qfeat[qloc][0]);
#pragma unroll 4
    for (int k = 0; k < C / 4; k++) {
      float4 rv = r4[k];
      float4 qv = q4[k];
      double d0 = (double)qv.x - (double)rv.x;
      dd = fma(d0, d0, dd);
      double d1 = (double)qv.y - (double)rv.y;
      dd = fma(d1, d1, dd);
      double d2 = (double)qv.z - (double)rv.z;
      dd = fma(d2, d2, dd);
      double d3 = (double)qv.w - (double)rv.w;
      dd = fma(d3, d3, dd);
    }
  } else {
    const float* r = rowB + (size_t)mc * C;
#pragma unroll
    for (int c = 0; c < C; c++) {
      double d0 = (double)qfeat[qloc][c] - (double)r[c];
      dd = fma(d0, d0, dd);
    }
  }
  int myi = (lane < cnt) ? mc : 0x7fffffff;
  if (lane >= cnt) dd = 1e300;
  // bitonic sort of 64 (dd, myi) pairs ascending; lanes 0..19 hold the top-20
#pragma unroll
  for (int k = 2; k <= 64; k <<= 1) {
#pragma unroll
    for (int j = k >> 1; j > 0; j >>= 1) {
      double od = __shfl_xor(dd, j, 64);
      int oi = __shfl_xor(myi, j, 64);
      bool up = (lane & k) == 0;
      bool lower = (lane & j) == 0;
      bool cmp = (od < dd) || (od == dd && oi < myi);  // other strictly smaller
      bool take = (up == lower) ? cmp : !cmp;
      if (take) {
        dd = od;
        myi = oi;
      }
    }
  }
  if (lane < KNN) op[lane] = myi;
}

// C=3: 8 queries per 256-thread block; each wave owns 2 queries; direct global reads.
template <int C>
__global__ void __launch_bounds__(256) knn_fused(const float* __restrict__ fT,
                                                 const float* __restrict__ rowF,
                                                 const float* __restrict__ sqf,
                                                 int* __restrict__ idx20) {
  __shared__ __align__(16) float qfeat[8][C];
  __shared__ int candBuf[8][64];
  int t = threadIdx.x, w = t >> 6, lane = t & 63;
  int q0 = blockIdx.x * 8;
  int b = q0 >> 11;
  for (int i = t; i < 8 * C; i += 256) qfeat[i / C][i % C] = rowF[(size_t)q0 * C + i];
  __syncthreads();
  const float* fTb = fT + (size_t)b * C * N;
  const float* rowB = rowF + (((size_t)b) << 11) * C;
  const float* sqb = sqf + (((size_t)b) << 11);
  int qa = w * 2, qbl = w * 2 + 1;
  float acc0[32], acc1[32];
#pragma unroll
  for (int j = 0; j < 32; j++) {
    acc0[j] = 0.f;
    acc1[j] = 0.f;
  }
  for (int c = 0; c < C; c++) {
    float qc0 = qfeat[qa][c], qc1 = qfeat[qbl][c];
    const float4* r4 = (const float4*)(fTb + (size_t)c * N);
#pragma unroll
    for (int j8 = 0; j8 < 8; j8++) {
      float4 v = r4[j8 * 64 + lane];
      acc0[4 * j8 + 0] = fmaf(v.x, qc0, acc0[4 * j8 + 0]);
      acc0[4 * j8 + 1] = fmaf(v.y, qc0, acc0[4 * j8 + 1]);
      acc0[4 * j8 + 2] = fmaf(v.z, qc0, acc0[4 * j8 + 2]);
      acc0[4 * j8 + 3] = fmaf(v.w, qc0, acc0[4 * j8 + 3]);
      acc1[4 * j8 + 0] = fmaf(v.x, qc1, acc1[4 * j8 + 0]);
      acc1[4 * j8 + 1] = fmaf(v.y, qc1, acc1[4 * j8 + 1]);
      acc1[4 * j8 + 2] = fmaf(v.z, qc1, acc1[4 * j8 + 2]);
      acc1[4 * j8 + 3] = fmaf(v.w, qc1, acc1[4 * j8 + 3]);
    }
  }
  select_refine<C>(acc0, lane, qa, sqb, rowB, qfeat, candBuf, idx20 + (size_t)(q0 + qa) * KNN);
  select_refine<C>(acc1, lane, qbl, sqb, rowB, qfeat, candBuf, idx20 + (size_t)(q0 + qbl) * KNN);
}

// C=64: LDS-staged dot phase; 16 queries per block, 4 per wave (each staged
// float4 feeds 16 FMAs). Staging double-buffered, issue-early/write-late.
__global__ void __launch_bounds__(256) knn_fused64(const float* __restrict__ fT,
                                                   const float* __restrict__ rowF,
                                                   const float* __restrict__ sqf,
                                                   int* __restrict__ idx20) {
  __shared__ __align__(16) float stage[2][2 * N];  // 32 KB
  __shared__ __align__(16) float qfeat[16][64];    // 4 KB
  __shared__ int candBuf[16][64];                  // 4 KB
  int t = threadIdx.x, w = t >> 6, lane = t & 63;
  int q0 = blockIdx.x * 16;
  int b = q0 >> 11;
  const float* fTb = fT + (size_t)b * 64 * N;
  const float4* src4 = (const float4*)fTb;  // row c = f4 [c*512 .. c*512+511]
  for (int i = t; i < 16 * 64; i += 256) qfeat[i >> 6][i & 63] = rowF[(size_t)q0 * 64 + i];

  // prologue: stage chunk 0 (channels 0,1)
  float4 st[4];
#pragma unroll
  for (int p = 0; p < 4; p++) st[p] = src4[t + 256 * p];
  {
    float4* d4 = (float4*)&stage[0][0];
#pragma unroll
    for (int p = 0; p < 4; p++) d4[t + 256 * p] = st[p];
  }
  __syncthreads();

  int qa = w * 4;
  float acc0[32], acc1[32], acc2[32], acc3[32];
#pragma unroll
  for (int j = 0; j < 32; j++) {
    acc0[j] = 0.f;
    acc1[j] = 0.f;
    acc2[j] = 0.f;
    acc3[j] = 0.f;
  }

  for (int chunk = 0; chunk < 32; chunk++) {
    int cur = chunk & 1;
    if (chunk < 31) {  // issue next chunk's loads early
#pragma unroll
      for (int p = 0; p < 4; p++) st[p] = src4[(chunk + 1) * 1024 + t + 256 * p];
    }
#pragma unroll
    for (int cc = 0; cc < 2; cc++) {
      int c = chunk * 2 + cc;
      float qc0 = qfeat[qa + 0][c], qc1 = qfeat[qa + 1][c];
      float qc2 = qfeat[qa + 2][c], qc3 = qfeat[qa + 3][c];
      const float4* r4 = (const float4*)&stage[cur][cc * N];
#pragma unroll
      for (int j8 = 0; j8 < 8; j8++) {
        float4 v = r4[j8 * 64 + lane];
        acc0[4 * j8 + 0] = fmaf(v.x, qc0, acc0[4 * j8 + 0]);
        acc0[4 * j8 + 1] = fmaf(v.y, qc0, acc0[4 * j8 + 1]);
        acc0[4 * j8 + 2] = fmaf(v.z, qc0, acc0[4 * j8 + 2]);
        acc0[4 * j8 + 3] = fmaf(v.w, qc0, acc0[4 * j8 + 3]);
        acc1[4 * j8 + 0] = fmaf(v.x, qc1, acc1[4 * j8 + 0]);
        acc1[4 * j8 + 1] = fmaf(v.y, qc1, acc1[4 * j8 + 1]);
        acc1[4 * j8 + 2] = fmaf(v.z, qc1, acc1[4 * j8 + 2]);
        acc1[4 * j8 + 3] = fmaf(v.w, qc1, acc1[4 * j8 + 3]);
        acc2[4 * j8 + 0] = fmaf(v.x, qc2, acc2[4 * j8 + 0]);
        acc2[4 * j8 + 1] = fmaf(v.y, qc2, acc2[4 * j8 + 1]);
        acc2[4 * j8 + 2] = fmaf(v.z, qc2, acc2[4 * j8 + 2]);
        acc2[4 * j8 + 3] = fmaf(v.w, qc2, acc2[4 * j8 + 3]);
        acc3[4 * j8 + 0] = fmaf(v.x, qc3, acc3[4 * j8 + 0]);
        acc3[4 * j8 + 1] = fmaf(v.y, qc3, acc3[4 * j8 + 1]);
        acc3[4 * j8 + 2] = fmaf(v.z, qc3, acc3[4 * j8 + 2]);
        acc3[4 * j8 + 3] = fmaf(v.w, qc3, acc3[4 * j8 + 3]);
      }
    }
    if (chunk < 31) {  // write-late into the other buffer
      float4* d4 = (float4*)&stage[cur ^ 1][0];
#pragma unroll
      for (int p = 0; p < 4; p++) d4[t + 256 * p] = st[p];
    }
    __syncthreads();
  }
  const float* rowB = rowF + (((size_t)b) << 11) * 64;
  const float* sqb = sqf + (((size_t)b) << 11);
  select_refine<64>(acc0, lane, qa + 0, sqb, rowB, qfeat, candBuf,
                    idx20 + (size_t)(q0 + qa + 0) * KNN);
  select_refine<64>(acc1, lane, qa + 1, sqb, rowB, qfeat, candBuf,
                    idx20 + (size_t)(q0 + qa + 1) * KNN);
  select_refine<64>(acc2, lane, qa + 2, sqb, rowB, qfeat, candBuf,
                    idx20 + (size_t)(q0 + qa + 2) * KNN);
  select_refine<64>(acc3, lane, qa + 3, sqb, rowB, qfeat, candBuf,
                    idx20 + (size_t)(q0 + qa + 3) * KNN);
}

// EdgeConv factorization: u' = A*(Wt - Wb) + bias, v = A*Wb.
template <int K, int D>
__global__ void __launch_bounds__(256) gemm_uv(const float* __restrict__ A,
                                               const float* __restrict__ W,
                                               const float* __restrict__ bias,
                                               float* __restrict__ u, float* __restrict__ v) {
  constexpr int RG = 256 / D;
  constexpr int RPT = 64 / RG;
  __shared__ float At[64][K];
  int t = threadIdx.x;
  int n0 = blockIdx.x * 64;
  for (int i = t; i < 64 * K; i += 256) At[i / K][i % K] = A[(size_t)n0 * K + i];
  __syncthreads();
  int col = t & (D - 1), rg = t / D;
  float au[RPT], av[RPT];
  float bb = bias[col];
#pragma unroll
  for (int r = 0; r < RPT; r++) {
    au[r] = bb;
    av[r] = 0.f;
  }
  for (int c = 0; c < K; c++) {
    float wt = W[(size_t)c * D + col];
    float wb = W[(size_t)(K + c) * D + col];
    float wu = wt - wb;
#pragma unroll
    for (int r = 0; r < RPT; r++) {
      float a = At[rg * RPT + r][c];
      au[r] = fmaf(a, wu, au[r]);
      av[r] = fmaf(a, wb, av[r]);
    }
  }
#pragma unroll
  for (int r = 0; r < RPT; r++) {
    u[(size_t)(n0 + rg * RPT + r) * D + col] = au[r];
    v[(size_t)(n0 + rg * RPT + r) * D + col] = av[r];
  }
}

// h[n,j,d] = relu(u'[n,d] + v[idx[n,j],d]); max/min over j + fp64 stats.
template <int D>
__global__ void __launch_bounds__(256) combine_max(const float* __restrict__ u,
                                                   const float* __restrict__ v,
                                                   const int* __restrict__ idx20,
                                                   float* __restrict__ hmax,
                                                   float* __restrict__ hmin,
                                                   double* __restrict__ sumP,
                                                   double* __restrict__ sqP) {
  constexpr int PPB = 256 / D;
  int t = threadIdx.x;
  int p = t / D, d = t & (D - 1);
  int bn = blockIdx.x * PPB + p;
  int b = bn >> 11;
  const int* ip = idx20 + (size_t)bn * KNN;
  float up = u[(size_t)bn * D + d];
  const float* vb = v + ((size_t)b << 11) * D;
  float mx = -1e30f, mn = 1e30f;
  double s = 0.0, q = 0.0;
#pragma unroll 4
  for (int j = 0; j < KNN; j++) {
    int nb = ip[j];
    float hv = up + vb[(size_t)nb * D + d];
    hv = hv > 0.f ? hv : 0.f;
    mx = fmaxf(mx, hv);
    mn = fminf(mn, hv);
    double hd = (double)hv;
    s += hd;
    q = fma(hd, hd, q);
  }
  hmax[(size_t)bn * D + d] = mx;
  hmin[(size_t)bn * D + d] = mn;
  int slot = bn & (NPART - 1);
  atomicAdd(&sumP[(size_t)slot * D + d], s);
  atomicAdd(&sqP[(size_t)slot * D + d], q);
}

__global__ void bn_finalize(const double* __restrict__ sumP, const double* __restrict__ sqP,
                            const float* __restrict__ g, const float* __restrict__ be,
                            float* __restrict__ scale, float* __restrict__ shift, int D,
                            double invM) {
  int d = blockIdx.x * 256 + threadIdx.x;
  if (d >= D) return;
  double s = 0.0, q = 0.0;
  for (int i = 0; i < NPART; i++) {
    s += sumP[i * D + d];
    q += sqP[i * D + d];
  }
  double mean = s * invM;
  double var = q * invM - mean * mean;
  double sc = (double)g[d] / sqrt(var + 1e-5);
  scale[d] = (float)sc;
  shift[d] = (float)((double)be[d] - mean * sc);
}

__global__ void bn_apply_max(const float* __restrict__ hmax, const float* __restrict__ hmin,
                             const float* __restrict__ scale, const float* __restrict__ shift,
                             float* __restrict__ out, int dmask, int total) {
  int i = blockIdx.x * 256 + threadIdx.x;
  if (i >= total) return;
  int d = i & dmask;
  float sc = scale[d];
  float v = sc >= 0.f ? hmax[i] : hmin[i];
  out[i] = v * sc + shift[d];
}

// [16384,320]x[320,1024]: block = 16 rows x 1024 cols; thread = 16 rows x 4
// contiguous cols; c unrolled x4 so At arrives as ds_read_b128.
__global__ void __launch_bounds__(256) final_gemm(const float* __restrict__ x1,
                                                  const float* __restrict__ x2,
                                                  const float* __restrict__ x3,
                                                  const float* __restrict__ x4,
                                                  const float* __restrict__ W5,
                                                  const float* __restrict__ b5,
                                                  unsigned int* __restrict__ h5max,
                                                  unsigned int* __restrict__ h5min,
                                                  double* __restrict__ sumP,
                                                  double* __restrict__ sqP) {
  __shared__ __align__(16) float At[16][320];  // 20 KB
  int t = threadIdx.x;
  int n0 = blockIdx.x * 16;
  int col = t * 4;
  for (int i = t; i < 16 * 320; i += 256) {
    int r = i / 320, c = i % 320;
    int n = n0 + r;
    float vv;
    if (c < 64) vv = x1[(size_t)n * 64 + c];
    else if (c < 128) vv = x2[(size_t)n * 64 + c - 64];
    else if (c < 192) vv = x3[(size_t)n * 64 + c - 128];
    else vv = x4[(size_t)n * 128 + c - 192];
    At[r][c] = vv;
  }
  __syncthreads();
  float4 acc[16];
  float4 bb = *(const float4*)(b5 + col);
#pragma unroll
  for (int r = 0; r < 16; r++) acc[r] = bb;
  for (int c4 = 0; c4 < 80; c4++) {
    const float* wbase = W5 + (size_t)c4 * 4 * 1024 + col;
    float4 w0 = *(const float4*)(wbase);
    float4 w1 = *(const float4*)(wbase + 1024);
    float4 w2 = *(const float4*)(wbase + 2048);
    float4 w3 = *(const float4*)(wbase + 3072);
#pragma unroll
    for (int r = 0; r < 16; r++) {
      float4 a = *(const float4*)(&At[r][c4 * 4]);
      acc[r].x = fmaf(a.x, w0.x, acc[r].x);
      acc[r].y = fmaf(a.x, w0.y, acc[r].y);
      acc[r].z = fmaf(a.x, w0.z, acc[r].z);
      acc[r].w = fmaf(a.x, w0.w, acc[r].w);
      acc[r].x = fmaf(a.y, w1.x, acc[r].x);
      acc[r].y = fmaf(a.y, w1.y, acc[r].y);
      acc[r].z = fmaf(a.y, w1.z, acc[r].z);
      acc[r].w = fmaf(a.y, w1.w, acc[r].w);
      acc[r].x = fmaf(a.z, w2.x, acc[r].x);
      acc[r].y = fmaf(a.z, w2.y, acc[r].y);
      acc[r].z = fmaf(a.z, w2.z, acc[r].z);
      acc[r].w = fmaf(a.z, w2.w, acc[r].w);
      acc[r].x = fmaf(a.w, w3.x, acc[r].x);
      acc[r].y = fmaf(a.w, w3.y, acc[r].y);
      acc[r].z = fmaf(a.w, w3.z, acc[r].z);
      acc[r].w = fmaf(a.w, w3.w, acc[r].w);
    }
  }
  int b = n0 >> 11;
  float mx[4] = {-1e30f, -1e30f, -1e30f, -1e30f};
  float mn[4] = {1e30f, 1e30f, 1e30f, 1e30f};
  double sv[4] = {0, 0, 0, 0}, qv[4] = {0, 0, 0, 0};
#pragma unroll
  for (int r = 0; r < 16; r++) {
    float h0 = acc[r].x > 0.f ? acc[r].x : 0.f;
    float h1 = acc[r].y > 0.f ? acc[r].y : 0.f;
    float h2 = acc[r].z > 0.f ? acc[r].z : 0.f;
    float h3 = acc[r].w > 0.f ? acc[r].w : 0.f;
    mx[0] = fmaxf(mx[0], h0);
    mn[0] = fminf(mn[0], h0);
    sv[0] += h0;
    qv[0] = fma((double)h0, (double)h0, qv[0]);
    mx[1] = fmaxf(mx[1], h1);
    mn[1] = fminf(mn[1], h1);
    sv[1] += h1;
    qv[1] = fma((double)h1, (double)h1, qv[1]);
    mx[2] = fmaxf(mx[2], h2);
    mn[2] = fminf(mn[2], h2);
    sv[2] += h2;
    qv[2] = fma((double)h2, (double)h2, qv[2]);
    mx[3] = fmaxf(mx[3], h3);
    mn[3] = fminf(mn[3], h3);
    sv[3] += h3;
    qv[3] = fma((double)h3, (double)h3, qv[3]);
  }
  int slot = blockIdx.x & (NPART - 1);
#pragma unroll
  for (int q = 0; q < 4; q++) {
    int ch = col + q;
    atomicMax(&h5max[(size_t)b * 1024 + ch], __float_as_uint(mx[q]));
    atomicMin(&h5min[(size_t)b * 1024 + ch], __float_as_uint(mn[q]));
    atomicAdd(&sumP[(size_t)slot * 1024 + ch], sv[q]);
    atomicAdd(&sqP[(size_t)slot * 1024 + ch], qv[q]);
  }
}

__global__ void final_apply(const unsigned int* __restrict__ h5max,
                            const unsigned int* __restrict__ h5min,
                            const float* __restrict__ scale, const float* __restrict__ shift,
                            float* __restrict__ out) {
  int i = blockIdx.x * 256 + threadIdx.x;
  if (i >= B * 1024) return;
  int ch = i & 1023;
  float sc = scale[ch];
  float v = __uint_as_float(sc >= 0.f ? h5max[i] : h5min[i]);
  out[i] = v * sc + shift[ch];
}

}  // namespace

extern "C" void kernel_launch(void* const* d_in, const int* in_sizes, int n_in,
                              void* d_out, int out_size, void* d_ws, size_t ws_size,
                              hipStream_t stream) {
  const float* x = (const float*)d_in[0];
  const float *Wv[5], *bv[5], *gv[5], *bev[5];
  for (int i = 0; i < 5; i++) {
    Wv[i] = (const float*)d_in[1 + 4 * i];
    bv[i] = (const float*)d_in[2 + 4 * i];
    gv[i] = (const float*)d_in[3 + 4 * i];
    bev[i] = (const float*)d_in[4 + 4 * i];
  }

  char* ws = (char*)d_ws;
  size_t off = 0;
  auto alloc = [&](size_t bytes) {
    size_t r = off;
    off = (off + bytes + 255) & ~(size_t)255;
    return r;
  };
  const int BN = B * N;
  float* feat0 = (float*)(ws + alloc((size_t)BN * 3 * 4));
  int* idx = (int*)(ws + alloc((size_t)BN * KNN * 4));
  float* x1 = (float*)(ws + alloc((size_t)BN * 64 * 4));
  float* x2 = (float*)(ws + alloc((size_t)BN * 64 * 4));
  float* x3 = (float*)(ws + alloc((size_t)BN * 64 * 4));
  float* x4 = (float*)(ws + alloc((size_t)BN * 128 * 4));
  float* xT = (float*)(ws + alloc((size_t)BN * 64 * 4));
  float* ub = (float*)(ws + alloc((size_t)BN * 128 * 4));
  float* vb = (float*)(ws + alloc((size_t)BN * 128 * 4));
  float* hmax = (float*)(ws + alloc((size_t)BN * 128 * 4));
  float* hmin = (float*)(ws + alloc((size_t)BN * 128 * 4));
  float* sqf = (float*)(ws + alloc((size_t)BN * 4));
  double* sumP = (double*)(ws + alloc((size_t)NPART * 1024 * 8));
  double* sqP = (double*)(ws + alloc((size_t)NPART * 1024 * 8));
  float* scale = (float*)(ws + alloc(1024 * 4));
  float* shift = (float*)(ws + alloc(1024 * 4));
  unsigned int* h5max = (unsigned int*)(ws + alloc((size_t)B * 1024 * 4));
  unsigned int* h5min = (unsigned int*)(ws + alloc((size_t)B * 1024 * 4));

  const double invMk = 1.0 / ((double)BN * KNN);
  dim3 tgrid(N / 32, 64 / 32, B);

  transpose_x<<<(BN * 3 + 255) / 256, 256, 0, stream>>>(x, feat0);

  // ---- layer 1: C=3 -> D=64 (x is already [B][3][N]) ----
  sqnormf3<<<(BN + 255) / 256, 256, 0, stream>>>(x, sqf);
  knn_fused<3><<<BN / 8, 256, 0, stream>>>(x, feat0, sqf, idx);
  gemm_uv<3, 64><<<BN / 64, 256, 0, stream>>>(feat0, Wv[0], bv[0], ub, vb);
  hipMemsetAsync(sumP, 0, NPART * 64 * 8, stream);
  hipMemsetAsync(sqP, 0, NPART * 64 * 8, stream);
  combine_max<64><<<BN / 4, 256, 0, stream>>>(ub, vb, idx, hmax, hmin, sumP, sqP);
  bn_finalize<<<1, 256, 0, stream>>>(sumP, sqP, gv[0], bev[0], scale, shift, 64, invMk);
  bn_apply_max<<<(BN * 64 + 255) / 256, 256, 0, stream>>>(hmax, hmin, scale, shift, x1, 63,
                                                          BN * 64);

  // ---- layer 2: C=64 -> D=64 ----
  transpose64<<<tgrid, 256, 0, stream>>>(x1, xT);
  sqnormf_row<<<BN / 4, 256, 0, stream>>>(x1, sqf);
  knn_fused64<<<BN / 16, 256, 0, stream>>>(xT, x1, sqf, idx);
  gemm_uv<64, 64><<<BN / 64, 256, 0, stream>>>(x1, Wv[1], bv[1], ub, vb);
  hipMemsetAsync(sumP, 0, NPART * 64 * 8, stream);
  hipMemsetAsync(sqP, 0, NPART * 64 * 8, stream);
  combine_max<64><<<BN / 4, 256, 0, stream>>>(ub, vb, idx, hmax, hmin, sumP, sqP);
  bn_finalize<<<1, 256, 0, stream>>>(sumP, sqP, gv[1], bev[1], scale, shift, 64, invMk);
  bn_apply_max<<<(BN * 64 + 255) / 256, 256, 0, stream>>>(hmax, hmin, scale, shift, x2, 63,
                                                          BN * 64);

  // ---- layer 3: C=64 -> D=64 ----
  transpose64<<<tgrid, 256, 0, stream>>>(x2, xT);
  sqnormf_row<<<BN / 4, 256, 0, stream>>>(x2, sqf);
  knn_fused64<<<BN / 16, 256, 0, stream>>>(xT, x2, sqf, idx);
  gemm_uv<64, 64><<<BN / 64, 256, 0, stream>>>(x2, Wv[2], bv[2], ub, vb);
  hipMemsetAsync(sumP, 0, NPART * 64 * 8, stream);
  hipMemsetAsync(sqP, 0, NPART * 64 * 8, stream);
  combine_max<64><<<BN / 4, 256, 0, stream>>>(ub, vb, idx, hmax, hmin, sumP, sqP);
  bn_finalize<<<1, 256, 0, stream>>>(sumP, sqP, gv[2], bev[2], scale, shift, 64, invMk);
  bn_apply_max<<<(BN * 64 + 255) / 256, 256, 0, stream>>>(hmax, hmin, scale, shift, x3, 63,
                                                          BN * 64);

  // ---- layer 4: C=64 -> D=128 ----
  transpose64<<<tgrid, 256, 0, stream>>>(x3, xT);
  sqnormf_row<<<BN / 4, 256, 0, stream>>>(x3, sqf);
  knn_fused64<<<BN / 16, 256, 0, stream>>>(xT, x3, sqf, idx);
  gemm_uv<64, 128><<<BN / 64, 256, 0, stream>>>(x3, Wv[3], bv[3], ub, vb);
  hipMemsetAsync(sumP, 0, NPART * 128 * 8, stream);
  hipMemsetAsync(sqP, 0, NPART * 128 * 8, stream);
  combine_max<128><<<BN / 2, 256, 0, stream>>>(ub, vb, idx, hmax, hmin, sumP, sqP);
  bn_finalize<<<1, 256, 0, stream>>>(sumP, sqP, gv[3], bev[3], scale, shift, 128, invMk);
  bn_apply_max<<<(BN * 128 + 255) / 256, 256, 0, stream>>>(hmax, hmin, scale, shift, x4, 127,
                                                           BN * 128);

  // ---- final: [BN,320] @ [320,1024], max over n ----
  hipMemsetAsync(sumP, 0, NPART * 1024 * 8, stream);
  hipMemsetAsync(sqP, 0, NPART * 1024 * 8, stream);
  hipMemsetAsync(h5max, 0, B * 1024 * 4, stream);
  hipMemsetAsync(h5min, 0x7f, B * 1024 * 4, stream);
  final_gemm<<<BN / 16, 256, 0, stream>>>(x1, x2, x3, x4, Wv[4], bv[4], h5max, h5min, sumP,
                                          sqP);
  bn_finalize<<<4, 256, 0, stream>>>(sumP, sqP, gv[4], bev[4], scale, shift, 1024,
                                     1.0 / (double)BN);
  final_apply<<<(B * 1024 + 255) / 256, 256, 0, stream>>>(h5max, h5min, scale, shift,
                                                          (float*)d_out);
}

// Round 7
// 956.170 us; speedup vs baseline: 7.6703x; 1.1396x over previous
//
#include <hip/hip_runtime.h>
#include <stdint.h>

namespace {

constexpr int B = 8, N = 2048, KNN = 20;
constexpr int NPART = 64;

// x [B][3][N] -> feat0 [B*N][3]
__global__ void transpose_x(const float* __restrict__ x, float* __restrict__ f) {
  int i = blockIdx.x * 256 + threadIdx.x;
  if (i >= B * N * 3) return;
  int c = i % 3, n = (i / 3) % N, b = i / (3 * N);
  f[i] = x[((size_t)b * 3 + c) * N + n];
}

// [B][N][64] -> [B][64][N], 32x32 LDS tiles
__global__ void transpose64(const float* __restrict__ in, float* __restrict__ out) {
  __shared__ float t[32][33];
  int b = blockIdx.z;
  int n0 = blockIdx.x * 32, c0 = blockIdx.y * 32;
  const float* ib = in + (size_t)b * N * 64;
  float* ob = out + (size_t)b * 64 * N;
  int tx = threadIdx.x & 31, ty = threadIdx.x >> 5;  // 32 x 8
#pragma unroll
  for (int i = 0; i < 32; i += 8) t[ty + i][tx] = ib[(size_t)(n0 + ty + i) * 64 + c0 + tx];
  __syncthreads();
#pragma unroll
  for (int i = 0; i < 32; i += 8) ob[(size_t)(c0 + ty + i) * N + n0 + tx] = t[tx][ty + i];
}

// fp32 squared norms from row-major [BN][64]
__global__ void sqnormf_row(const float* __restrict__ x, float* __restrict__ sqf) {
  int bn = blockIdx.x * 4 + (threadIdx.x >> 6);
  int lane = threadIdx.x & 63;
  float v = x[(size_t)bn * 64 + lane];
  float s = v * v;
#pragma unroll
  for (int off = 32; off; off >>= 1) s += __shfl_xor(s, off, 64);
  if (lane == 0) sqf[bn] = s;
}

// fp32 squared norms from x [B][3][N]
__global__ void sqnormf3(const float* __restrict__ x, float* __restrict__ sqf) {
  int i = blockIdx.x * 256 + threadIdx.x;
  if (i >= B * N) return;
  int b = i >> 11, n = i & (N - 1);
  const float* xb = x + (size_t)b * 3 * N;
  float s = 0.f;
#pragma unroll
  for (int c = 0; c < 3; c++) {
    float v = xb[(size_t)c * N + n];
    s = fmaf(v, v, s);
  }
  sqf[i] = s;
}

// Wave-wide min, result in ALL lanes. row_ror DPP (VALU-speed, no OOB lanes)
// for the 4 in-row steps + 2 shfl_xor for the cross-row steps.
__device__ __forceinline__ float wave_min_f32(float x) {
  int t;
  t = __builtin_amdgcn_update_dpp(__float_as_int(x), __float_as_int(x), 0x121, 0xf, 0xf, false);
  x = fminf(x, __int_as_float(t));
  t = __builtin_amdgcn_update_dpp(__float_as_int(x), __float_as_int(x), 0x122, 0xf, 0xf, false);
  x = fminf(x, __int_as_float(t));
  t = __builtin_amdgcn_update_dpp(__float_as_int(x), __float_as_int(x), 0x124, 0xf, 0xf, false);
  x = fminf(x, __int_as_float(t));
  t = __builtin_amdgcn_update_dpp(__float_as_int(x), __float_as_int(x), 0x128, 0xf, 0xf, false);
  x = fminf(x, __int_as_float(t));
  x = fminf(x, __shfl_xor(x, 16, 64));
  x = fminf(x, __shfl_xor(x, 32, 64));
  return x;
}

// fp32 candidate selection + fp64 exact refine for TWO queries, phases
// interleaved so every serial chain has 2 independent streams.
// A[32] holds dot(q, point) on entry for points pt(k) = (k>>2)*256 + lane*4 + (k&3).
template <int C>
__device__ __forceinline__ void select_refine2(float (&A0)[32], float (&A1)[32], int lane,
                                               int q0loc, int q1loc,
                                               const float* __restrict__ sqb,
                                               const float* __restrict__ rowB,
                                               const float (*qfeat)[C], int (*candBuf)[64],
                                               int* __restrict__ op0, int* __restrict__ op1) {
  // dot -> comparison distance d = |m|^2 - 2*dot (query-norm constant dropped)
  const float4* sq4 = (const float4*)sqb;
#pragma unroll
  for (int j8 = 0; j8 < 8; j8++) {
    float4 sv = sq4[j8 * 64 + lane];
    A0[4 * j8 + 0] = fmaf(-2.f, A0[4 * j8 + 0], sv.x);
    A0[4 * j8 + 1] = fmaf(-2.f, A0[4 * j8 + 1], sv.y);
    A0[4 * j8 + 2] = fmaf(-2.f, A0[4 * j8 + 2], sv.z);
    A0[4 * j8 + 3] = fmaf(-2.f, A0[4 * j8 + 3], sv.w);
    A1[4 * j8 + 0] = fmaf(-2.f, A1[4 * j8 + 0], sv.x);
    A1[4 * j8 + 1] = fmaf(-2.f, A1[4 * j8 + 1], sv.y);
    A1[4 * j8 + 2] = fmaf(-2.f, A1[4 * j8 + 2], sv.z);
    A1[4 * j8 + 3] = fmaf(-2.f, A1[4 * j8 + 3], sv.w);
  }
  // per-lane branchless sorted top-8 (ascending), both queries interleaved
  float s0[8], s1[8];
#pragma unroll
  for (int i = 0; i < 8; i++) {
    s0[i] = 1e30f;
    s1[i] = 1e30f;
  }
#pragma unroll
  for (int k = 0; k < 32; k++) {
    float t0 = A0[k], t1 = A1[k];
#pragma unroll
    for (int i = 0; i < 8; i++) {
      float lo0 = fminf(s0[i], t0);
      t0 = fmaxf(s0[i], t0);
      s0[i] = lo0;
      float lo1 = fminf(s1[i], t1);
      t1 = fmaxf(s1[i], t1);
      s1[i] = lo1;
    }
  }
  // 32 wave-min pops -> threshold T at rank >= 32 (exact-or-larger: superset-safe)
  float T0 = 0.f, T1 = 0.f;
  for (int it = 0; it < 32; it++) {
    float m0 = wave_min_f32(s0[0]);
    float m1 = wave_min_f32(s1[0]);
    bool w0 = (s0[0] == m0);
    bool w1 = (s1[0] == m1);
#pragma unroll
    for (int i = 0; i < 7; i++) {
      s0[i] = w0 ? s0[i + 1] : s0[i];
      s1[i] = w1 ? s1[i + 1] : s1[i];
    }
    s0[7] = w0 ? 1e30f : s0[7];
    s1[7] = w1 ? 1e30f : s1[7];
    T0 = m0;
    T1 = m1;
  }
  // ballot-compact candidates (d <= T) into LDS
  int base0 = 0, base1 = 0;
#pragma unroll
  for (int k = 0; k < 32; k++) {
    int pt = (k >> 2) * 256 + lane * 4 + (k & 3);
    bool p0 = (A0[k] <= T0);
    unsigned long long mk0 = __ballot(p0);
    if (p0) {
      int pos = base0 + (int)__popcll(mk0 & ((1ull << lane) - 1));
      if (pos < 64) candBuf[q0loc][pos] = pt;
    }
    base0 += (int)__popcll(mk0);
    bool p1 = (A1[k] <= T1);
    unsigned long long mk1 = __ballot(p1);
    if (p1) {
      int pos = base1 + (int)__popcll(mk1 & ((1ull << lane) - 1));
      if (pos < 64) candBuf[q1loc][pos] = pt;
    }
    base1 += (int)__popcll(mk1);
  }
  int cnt0 = base0 < 64 ? base0 : 64;
  int cnt1 = base1 < 64 ? base1 : 64;
  // fp64 exact distances (difference formula), both gathers in flight together
  int mc0 = (lane < cnt0) ? candBuf[q0loc][lane] : 0;
  int mc1 = (lane < cnt1) ? candBuf[q1loc][lane] : 0;
  double dd0 = 0.0, dd1 = 0.0;
  if constexpr (C % 4 == 0) {
    const float4* r40 = (const float4*)(rowB + (size_t)mc0 * C);
    const float4* r41 = (const float4*)(rowB + (size_t)mc1 * C);
    const float4* q40 = (const float4*)(&qfeat[q0loc][0]);
    const float4* q41 = (const float4*)(&qfeat[q1loc][0]);
#pragma unroll 4
    for (int k = 0; k < C / 4; k++) {
      float4 rv0 = r40[k], qv0 = q40[k];
      float4 rv1 = r41[k], qv1 = q41[k];
      double e0 = (double)qv0.x - (double)rv0.x;
      dd0 = fma(e0, e0, dd0);
      double e1 = (double)qv0.y - (double)rv0.y;
      dd0 = fma(e1, e1, dd0);
      double e2 = (double)qv0.z - (double)rv0.z;
      dd0 = fma(e2, e2, dd0);
      double e3 = (double)qv0.w - (double)rv0.w;
      dd0 = fma(e3, e3, dd0);
      double f0 = (double)qv1.x - (double)rv1.x;
      dd1 = fma(f0, f0, dd1);
      double f1 = (double)qv1.y - (double)rv1.y;
      dd1 = fma(f1, f1, dd1);
      double f2 = (double)qv1.z - (double)rv1.z;
      dd1 = fma(f2, f2, dd1);
      double f3 = (double)qv1.w - (double)rv1.w;
      dd1 = fma(f3, f3, dd1);
    }
  } else {
    const float* r0 = rowB + (size_t)mc0 * C;
    const float* r1 = rowB + (size_t)mc1 * C;
#pragma unroll
    for (int c = 0; c < C; c++) {
      double e0 = (double)qfeat[q0loc][c] - (double)r0[c];
      dd0 = fma(e0, e0, dd0);
      double e1 = (double)qfeat[q1loc][c] - (double)r1[c];
      dd1 = fma(e1, e1, dd1);
    }
  }
  int myi0 = (lane < cnt0) ? mc0 : 0x7fffffff;
  int myi1 = (lane < cnt1) ? mc1 : 0x7fffffff;
  if (lane >= cnt0) dd0 = 1e300;
  if (lane >= cnt1) dd1 = 1e300;
  // bitonic sort of 64 (dd, idx) pairs ascending, both queries interleaved
#pragma unroll
  for (int k = 2; k <= 64; k <<= 1) {
#pragma unroll
    for (int j = k >> 1; j > 0; j >>= 1) {
      double od0 = __shfl_xor(dd0, j, 64);
      int oi0 = __shfl_xor(myi0, j, 64);
      double od1 = __shfl_xor(dd1, j, 64);
      int oi1 = __shfl_xor(myi1, j, 64);
      bool up = (lane & k) == 0;
      bool lower = (lane & j) == 0;
      bool dir = (up == lower);
      bool cmp0 = (od0 < dd0) || (od0 == dd0 && oi0 < myi0);
      if (dir ? cmp0 : !cmp0) {
        dd0 = od0;
        myi0 = oi0;
      }
      bool cmp1 = (od1 < dd1) || (od1 == dd1 && oi1 < myi1);
      if (dir ? cmp1 : !cmp1) {
        dd1 = od1;
        myi1 = oi1;
      }
    }
  }
  if (lane < KNN) {
    op0[lane] = myi0;
    op1[lane] = myi1;
  }
}

// C=3: 8 queries per 256-thread block; each wave owns 2 queries; direct global reads.
template <int C>
__global__ void __launch_bounds__(256) knn_fused(const float* __restrict__ fT,
                                                 const float* __restrict__ rowF,
                                                 const float* __restrict__ sqf,
                                                 int* __restrict__ idx20) {
  __shared__ __align__(16) float qfeat[8][C];
  __shared__ int candBuf[8][64];
  int t = threadIdx.x, w = t >> 6, lane = t & 63;
  int q0 = blockIdx.x * 8;
  int b = q0 >> 11;
  for (int i = t; i < 8 * C; i += 256) qfeat[i / C][i % C] = rowF[(size_t)q0 * C + i];
  __syncthreads();
  const float* fTb = fT + (size_t)b * C * N;
  const float* rowB = rowF + (((size_t)b) << 11) * C;
  const float* sqb = sqf + (((size_t)b) << 11);
  int qa = w * 2, qbl = w * 2 + 1;
  float acc0[32], acc1[32];
#pragma unroll
  for (int j = 0; j < 32; j++) {
    acc0[j] = 0.f;
    acc1[j] = 0.f;
  }
  for (int c = 0; c < C; c++) {
    float qc0 = qfeat[qa][c], qc1 = qfeat[qbl][c];
    const float4* r4 = (const float4*)(fTb + (size_t)c * N);
#pragma unroll
    for (int j8 = 0; j8 < 8; j8++) {
      float4 v = r4[j8 * 64 + lane];
      acc0[4 * j8 + 0] = fmaf(v.x, qc0, acc0[4 * j8 + 0]);
      acc0[4 * j8 + 1] = fmaf(v.y, qc0, acc0[4 * j8 + 1]);
      acc0[4 * j8 + 2] = fmaf(v.z, qc0, acc0[4 * j8 + 2]);
      acc0[4 * j8 + 3] = fmaf(v.w, qc0, acc0[4 * j8 + 3]);
      acc1[4 * j8 + 0] = fmaf(v.x, qc1, acc1[4 * j8 + 0]);
      acc1[4 * j8 + 1] = fmaf(v.y, qc1, acc1[4 * j8 + 1]);
      acc1[4 * j8 + 2] = fmaf(v.z, qc1, acc1[4 * j8 + 2]);
      acc1[4 * j8 + 3] = fmaf(v.w, qc1, acc1[4 * j8 + 3]);
    }
  }
  select_refine2<C>(acc0, acc1, lane, qa, qbl, sqb, rowB, qfeat, candBuf,
                    idx20 + (size_t)(q0 + qa) * KNN, idx20 + (size_t)(q0 + qbl) * KNN);
}

// C=64: LDS-staged dot phase; 16 queries per block, 4 per wave (each staged
// float4 feeds 16 FMAs). Staging double-buffered, issue-early/write-late.
__global__ void __launch_bounds__(256) knn_fused64(const float* __restrict__ fT,
                                                   const float* __restrict__ rowF,
                                                   const float* __restrict__ sqf,
                                                   int* __restrict__ idx20) {
  __shared__ __align__(16) float stage[2][2 * N];  // 32 KB
  __shared__ __align__(16) float qfeat[16][64];    // 4 KB
  __shared__ int candBuf[16][64];                  // 4 KB
  int t = threadIdx.x, w = t >> 6, lane = t & 63;
  int q0 = blockIdx.x * 16;
  int b = q0 >> 11;
  const float* fTb = fT + (size_t)b * 64 * N;
  const float4* src4 = (const float4*)fTb;  // row c = f4 [c*512 .. c*512+511]
  for (int i = t; i < 16 * 64; i += 256) qfeat[i >> 6][i & 63] = rowF[(size_t)q0 * 64 + i];

  // prologue: stage chunk 0 (channels 0,1)
  float4 st[4];
#pragma unroll
  for (int p = 0; p < 4; p++) st[p] = src4[t + 256 * p];
  {
    float4* d4 = (float4*)&stage[0][0];
#pragma unroll
    for (int p = 0; p < 4; p++) d4[t + 256 * p] = st[p];
  }
  __syncthreads();

  int qa = w * 4;
  float acc0[32], acc1[32], acc2[32], acc3[32];
#pragma unroll
  for (int j = 0; j < 32; j++) {
    acc0[j] = 0.f;
    acc1[j] = 0.f;
    acc2[j] = 0.f;
    acc3[j] = 0.f;
  }

  for (int chunk = 0; chunk < 32; chunk++) {
    int cur = chunk & 1;
    if (chunk < 31) {  // issue next chunk's loads early
#pragma unroll
      for (int p = 0; p < 4; p++) st[p] = src4[(chunk + 1) * 1024 + t + 256 * p];
    }
#pragma unroll
    for (int cc = 0; cc < 2; cc++) {
      int c = chunk * 2 + cc;
      float qc0 = qfeat[qa + 0][c], qc1 = qfeat[qa + 1][c];
      float qc2 = qfeat[qa + 2][c], qc3 = qfeat[qa + 3][c];
      const float4* r4 = (const float4*)&stage[cur][cc * N];
#pragma unroll
      for (int j8 = 0; j8 < 8; j8++) {
        float4 v = r4[j8 * 64 + lane];
        acc0[4 * j8 + 0] = fmaf(v.x, qc0, acc0[4 * j8 + 0]);
        acc0[4 * j8 + 1] = fmaf(v.y, qc0, acc0[4 * j8 + 1]);
        acc0[4 * j8 + 2] = fmaf(v.z, qc0, acc0[4 * j8 + 2]);
        acc0[4 * j8 + 3] = fmaf(v.w, qc0, acc0[4 * j8 + 3]);
        acc1[4 * j8 + 0] = fmaf(v.x, qc1, acc1[4 * j8 + 0]);
        acc1[4 * j8 + 1] = fmaf(v.y, qc1, acc1[4 * j8 + 1]);
        acc1[4 * j8 + 2] = fmaf(v.z, qc1, acc1[4 * j8 + 2]);
        acc1[4 * j8 + 3] = fmaf(v.w, qc1, acc1[4 * j8 + 3]);
        acc2[4 * j8 + 0] = fmaf(v.x, qc2, acc2[4 * j8 + 0]);
        acc2[4 * j8 + 1] = fmaf(v.y, qc2, acc2[4 * j8 + 1]);
        acc2[4 * j8 + 2] = fmaf(v.z, qc2, acc2[4 * j8 + 2]);
        acc2[4 * j8 + 3] = fmaf(v.w, qc2, acc2[4 * j8 + 3]);
        acc3[4 * j8 + 0] = fmaf(v.x, qc3, acc3[4 * j8 + 0]);
        acc3[4 * j8 + 1] = fmaf(v.y, qc3, acc3[4 * j8 + 1]);
        acc3[4 * j8 + 2] = fmaf(v.z, qc3, acc3[4 * j8 + 2]);
        acc3[4 * j8 + 3] = fmaf(v.w, qc3, acc3[4 * j8 + 3]);
      }
    }
    if (chunk < 31) {  // write-late into the other buffer
      float4* d4 = (float4*)&stage[cur ^ 1][0];
#pragma unroll
      for (int p = 0; p < 4; p++) d4[t + 256 * p] = st[p];
    }
    __syncthreads();
  }
  const float* rowB = rowF + (((size_t)b) << 11) * 64;
  const float* sqb = sqf + (((size_t)b) << 11);
  select_refine2<64>(acc0, acc1, lane, qa + 0, qa + 1, sqb, rowB, qfeat, candBuf,
                     idx20 + (size_t)(q0 + qa + 0) * KNN, idx20 + (size_t)(q0 + qa + 1) * KNN);
  select_refine2<64>(acc2, acc3, lane, qa + 2, qa + 3, sqb, rowB, qfeat, candBuf,
                     idx20 + (size_t)(q0 + qa + 2) * KNN, idx20 + (size_t)(q0 + qa + 3) * KNN);
}

// EdgeConv factorization: u' = A*(Wt - Wb) + bias, v = A*Wb.
template <int K, int D>
__global__ void __launch_bounds__(256) gemm_uv(const float* __restrict__ A,
                                               const float* __restrict__ W,
                                               const float* __restrict__ bias,
                                               float* __restrict__ u, float* __restrict__ v) {
  constexpr int RG = 256 / D;
  constexpr int RPT = 64 / RG;
  __shared__ float At[64][K];
  int t = threadIdx.x;
  int n0 = blockIdx.x * 64;
  for (int i = t; i < 64 * K; i += 256) At[i / K][i % K] = A[(size_t)n0 * K + i];
  __syncthreads();
  int col = t & (D - 1), rg = t / D;
  float au[RPT], av[RPT];
  float bb = bias[col];
#pragma unroll
  for (int r = 0; r < RPT; r++) {
    au[r] = bb;
    av[r] = 0.f;
  }
  for (int c = 0; c < K; c++) {
    float wt = W[(size_t)c * D + col];
    float wb = W[(size_t)(K + c) * D + col];
    float wu = wt - wb;
#pragma unroll
    for (int r = 0; r < RPT; r++) {
      float a = At[rg * RPT + r][c];
      au[r] = fmaf(a, wu, au[r]);
      av[r] = fmaf(a, wb, av[r]);
    }
  }
#pragma unroll
  for (int r = 0; r < RPT; r++) {
    u[(size_t)(n0 + rg * RPT + r) * D + col] = au[r];
    v[(size_t)(n0 + rg * RPT + r) * D + col] = av[r];
  }
}

// h[n,j,d] = relu(u'[n,d] + v[idx[n,j],d]); max/min over j + fp64 stats.
template <int D>
__global__ void __launch_bounds__(256) combine_max(const float* __restrict__ u,
                                                   const float* __restrict__ v,
                                                   const int* __restrict__ idx20,
                                                   float* __restrict__ hmax,
                                                   float* __restrict__ hmin,
                                                   double* __restrict__ sumP,
                                                   double* __restrict__ sqP) {
  constexpr int PPB = 256 / D;
  int t = threadIdx.x;
  int p = t / D, d = t & (D - 1);
  int bn = blockIdx.x * PPB + p;
  int b = bn >> 11;
  const int* ip = idx20 + (size_t)bn * KNN;
  float up = u[(size_t)bn * D + d];
  const float* vb = v + ((size_t)b << 11) * D;
  float mx = -1e30f, mn = 1e30f;
  double s = 0.0, q = 0.0;
#pragma unroll 4
  for (int j = 0; j < KNN; j++) {
    int nb = ip[j];
    float hv = up + vb[(size_t)nb * D + d];
    hv = hv > 0.f ? hv : 0.f;
    mx = fmaxf(mx, hv);
    mn = fminf(mn, hv);
    double hd = (double)hv;
    s += hd;
    q = fma(hd, hd, q);
  }
  hmax[(size_t)bn * D + d] = mx;
  hmin[(size_t)bn * D + d] = mn;
  int slot = bn & (NPART - 1);
  atomicAdd(&sumP[(size_t)slot * D + d], s);
  atomicAdd(&sqP[(size_t)slot * D + d], q);
}

__global__ void bn_finalize(const double* __restrict__ sumP, const double* __restrict__ sqP,
                            const float* __restrict__ g, const float* __restrict__ be,
                            float* __restrict__ scale, float* __restrict__ shift, int D,
                            double invM) {
  int d = blockIdx.x * 256 + threadIdx.x;
  if (d >= D) return;
  double s = 0.0, q = 0.0;
  for (int i = 0; i < NPART; i++) {
    s += sumP[i * D + d];
    q += sqP[i * D + d];
  }
  double mean = s * invM;
  double var = q * invM - mean * mean;
  double sc = (double)g[d] / sqrt(var + 1e-5);
  scale[d] = (float)sc;
  shift[d] = (float)((double)be[d] - mean * sc);
}

__global__ void bn_apply_max(const float* __restrict__ hmax, const float* __restrict__ hmin,
                             const float* __restrict__ scale, const float* __restrict__ shift,
                             float* __restrict__ out, int dmask, int total) {
  int i = blockIdx.x * 256 + threadIdx.x;
  if (i >= total) return;
  int d = i & dmask;
  float sc = scale[d];
  float v = sc >= 0.f ? hmax[i] : hmin[i];
  out[i] = v * sc + shift[d];
}

// [16384,320]x[320,1024]: block = 16 rows x 1024 cols; thread = 16 rows x 4
// contiguous cols; c unrolled x4 so At arrives as ds_read_b128.
__global__ void __launch_bounds__(256) final_gemm(const float* __restrict__ x1,
                                                  const float* __restrict__ x2,
                                                  const float* __restrict__ x3,
                                                  const float* __restrict__ x4,
                                                  const float* __restrict__ W5,
                                                  const float* __restrict__ b5,
                                                  unsigned int* __restrict__ h5max,
                                                  unsigned int* __restrict__ h5min,
                                                  double* __restrict__ sumP,
                                                  double* __restrict__ sqP) {
  __shared__ __align__(16) float At[16][320];  // 20 KB
  int t = threadIdx.x;
  int n0 = blockIdx.x * 16;
  int col = t * 4;
  for (int i = t; i < 16 * 320; i += 256) {
    int r = i / 320, c = i % 320;
    int n = n0 + r;
    float vv;
    if (c < 64) vv = x1[(size_t)n * 64 + c];
    else if (c < 128) vv = x2[(size_t)n * 64 + c - 64];
    else if (c < 192) vv = x3[(size_t)n * 64 + c - 128];
    else vv = x4[(size_t)n * 128 + c - 192];
    At[r][c] = vv;
  }
  __syncthreads();
  float4 acc[16];
  float4 bb = *(const float4*)(b5 + col);
#pragma unroll
  for (int r = 0; r < 16; r++) acc[r] = bb;
  for (int c4 = 0; c4 < 80; c4++) {
    const float* wbase = W5 + (size_t)c4 * 4 * 1024 + col;
    float4 w0 = *(const float4*)(wbase);
    float4 w1 = *(const float4*)(wbase + 1024);
    float4 w2 = *(const float4*)(wbase + 2048);
    float4 w3 = *(const float4*)(wbase + 3072);
#pragma unroll
    for (int r = 0; r < 16; r++) {
      float4 a = *(const float4*)(&At[r][c4 * 4]);
      acc[r].x = fmaf(a.x, w0.x, acc[r].x);
      acc[r].y = fmaf(a.x, w0.y, acc[r].y);
      acc[r].z = fmaf(a.x, w0.z, acc[r].z);
      acc[r].w = fmaf(a.x, w0.w, acc[r].w);
      acc[r].x = fmaf(a.y, w1.x, acc[r].x);
      acc[r].y = fmaf(a.y, w1.y, acc[r].y);
      acc[r].z = fmaf(a.y, w1.z, acc[r].z);
      acc[r].w = fmaf(a.y, w1.w, acc[r].w);
      acc[r].x = fmaf(a.z, w2.x, acc[r].x);
      acc[r].y = fmaf(a.z, w2.y, acc[r].y);
      acc[r].z = fmaf(a.z, w2.z, acc[r].z);
      acc[r].w = fmaf(a.z, w2.w, acc[r].w);
      acc[r].x = fmaf(a.w, w3.x, acc[r].x);
      acc[r].y = fmaf(a.w, w3.y, acc[r].y);
      acc[r].z = fmaf(a.w, w3.z, acc[r].z);
      acc[r].w = fmaf(a.w, w3.w, acc[r].w);
    }
  }
  int b = n0 >> 11;
  float mx[4] = {-1e30f, -1e30f, -1e30f, -1e30f};
  float mn[4] = {1e30f, 1e30f, 1e30f, 1e30f};
  double sv[4] = {0, 0, 0, 0}, qv[4] = {0, 0, 0, 0};
#pragma unroll
  for (int r = 0; r < 16; r++) {
    float h0 = acc[r].x > 0.f ? acc[r].x : 0.f;
    float h1 = acc[r].y > 0.f ? acc[r].y : 0.f;
    float h2 = acc[r].z > 0.f ? acc[r].z : 0.f;
    float h3 = acc[r].w > 0.f ? acc[r].w : 0.f;
    mx[0] = fmaxf(mx[0], h0);
    mn[0] = fminf(mn[0], h0);
    sv[0] += h0;
    qv[0] = fma((double)h0, (double)h0, qv[0]);
    mx[1] = fmaxf(mx[1], h1);
    mn[1] = fminf(mn[1], h1);
    sv[1] += h1;
    qv[1] = fma((double)h1, (double)h1, qv[1]);
    mx[2] = fmaxf(mx[2], h2);
    mn[2] = fminf(mn[2], h2);
    sv[2] += h2;
    qv[2] = fma((double)h2, (double)h2, qv[2]);
    mx[3] = fmaxf(mx[3], h3);
    mn[3] = fminf(mn[3], h3);
    sv[3] += h3;
    qv[3] = fma((double)h3, (double)h3, qv[3]);
  }
  int slot = blockIdx.x & (NPART - 1);
#pragma unroll
  for (int q = 0; q < 4; q++) {
    int ch = col + q;
    atomicMax(&h5max[(size_t)b * 1024 + ch], __float_as_uint(mx[q]));
    atomicMin(&h5min[(size_t)b * 1024 + ch], __float_as_uint(mn[q]));
    atomicAdd(&sumP[(size_t)slot * 1024 + ch], sv[q]);
    atomicAdd(&sqP[(size_t)slot * 1024 + ch], qv[q]);
  }
}

__global__ void final_apply(const unsigned int* __restrict__ h5max,
                            const unsigned int* __restrict__ h5min,
                            const float* __restrict__ scale, const float* __restrict__ shift,
                            float* __restrict__ out) {
  int i = blockIdx.x * 256 + threadIdx.x;
  if (i >= B * 1024) return;
  int ch = i & 1023;
  float sc = scale[ch];
  float v = __uint_as_float(sc >= 0.f ? h5max[i] : h5min[i]);
  out[i] = v * sc + shift[ch];
}

}  // namespace

extern "C" void kernel_launch(void* const* d_in, const int* in_sizes, int n_in,
                              void* d_out, int out_size, void* d_ws, size_t ws_size,
                              hipStream_t stream) {
  const float* x = (const float*)d_in[0];
  const float *Wv[5], *bv[5], *gv[5], *bev[5];
  for (int i = 0; i < 5; i++) {
    Wv[i] = (const float*)d_in[1 + 4 * i];
    bv[i] = (const float*)d_in[2 + 4 * i];
    gv[i] = (const float*)d_in[3 + 4 * i];
    bev[i] = (const float*)d_in[4 + 4 * i];
  }

  char* ws = (char*)d_ws;
  size_t off = 0;
  auto alloc = [&](size_t bytes) {
    size_t r = off;
    off = (off + bytes + 255) & ~(size_t)255;
    return r;
  };
  const int BN = B * N;
  float* feat0 = (float*)(ws + alloc((size_t)BN * 3 * 4));
  int* idx = (int*)(ws + alloc((size_t)BN * KNN * 4));
  float* x1 = (float*)(ws + alloc((size_t)BN * 64 * 4));
  float* x2 = (float*)(ws + alloc((size_t)BN * 64 * 4));
  float* x3 = (float*)(ws + alloc((size_t)BN * 64 * 4));
  float* x4 = (float*)(ws + alloc((size_t)BN * 128 * 4));
  float* xT = (float*)(ws + alloc((size_t)BN * 64 * 4));
  float* ub = (float*)(ws + alloc((size_t)BN * 128 * 4));
  float* vb = (float*)(ws + alloc((size_t)BN * 128 * 4));
  float* hmax = (float*)(ws + alloc((size_t)BN * 128 * 4));
  float* hmin = (float*)(ws + alloc((size_t)BN * 128 * 4));
  float* sqf = (float*)(ws + alloc((size_t)BN * 4));
  double* sumP = (double*)(ws + alloc((size_t)NPART * 1024 * 8));
  double* sqP = (double*)(ws + alloc((size_t)NPART * 1024 * 8));
  float* scale = (float*)(ws + alloc(1024 * 4));
  float* shift = (float*)(ws + alloc(1024 * 4));
  unsigned int* h5max = (unsigned int*)(ws + alloc((size_t)B * 1024 * 4));
  unsigned int* h5min = (unsigned int*)(ws + alloc((size_t)B * 1024 * 4));

  const double invMk = 1.0 / ((double)BN * KNN);
  dim3 tgrid(N / 32, 64 / 32, B);

  transpose_x<<<(BN * 3 + 255) / 256, 256, 0, stream>>>(x, feat0);

  // ---- layer 1: C=3 -> D=64 (x is already [B][3][N]) ----
  sqnormf3<<<(BN + 255) / 256, 256, 0, stream>>>(x, sqf);
  knn_fused<3><<<BN / 8, 256, 0, stream>>>(x, feat0, sqf, idx);
  gemm_uv<3, 64><<<BN / 64, 256, 0, stream>>>(feat0, Wv[0], bv[0], ub, vb);
  hipMemsetAsync(sumP, 0, NPART * 64 * 8, stream);
  hipMemsetAsync(sqP, 0, NPART * 64 * 8, stream);
  combine_max<64><<<BN / 4, 256, 0, stream>>>(ub, vb, idx, hmax, hmin, sumP, sqP);
  bn_finalize<<<1, 256, 0, stream>>>(sumP, sqP, gv[0], bev[0], scale, shift, 64, invMk);
  bn_apply_max<<<(BN * 64 + 255) / 256, 256, 0, stream>>>(hmax, hmin, scale, shift, x1, 63,
                                                          BN * 64);

  // ---- layer 2: C=64 -> D=64 ----
  transpose64<<<tgrid, 256, 0, stream>>>(x1, xT);
  sqnormf_row<<<BN / 4, 256, 0, stream>>>(x1, sqf);
  knn_fused64<<<BN / 16, 256, 0, stream>>>(xT, x1, sqf, idx);
  gemm_uv<64, 64><<<BN / 64, 256, 0, stream>>>(x1, Wv[1], bv[1], ub, vb);
  hipMemsetAsync(sumP, 0, NPART * 64 * 8, stream);
  hipMemsetAsync(sqP, 0, NPART * 64 * 8, stream);
  combine_max<64><<<BN / 4, 256, 0, stream>>>(ub, vb, idx, hmax, hmin, sumP, sqP);
  bn_finalize<<<1, 256, 0, stream>>>(sumP, sqP, gv[1], bev[1], scale, shift, 64, invMk);
  bn_apply_max<<<(BN * 64 + 255) / 256, 256, 0, stream>>>(hmax, hmin, scale, shift, x2, 63,
                                                          BN * 64);

  // ---- layer 3: C=64 -> D=64 ----
  transpose64<<<tgrid, 256, 0, stream>>>(x2, xT);
  sqnormf_row<<<BN / 4, 256, 0, stream>>>(x2, sqf);
  knn_fused64<<<BN / 16, 256, 0, stream>>>(xT, x2, sqf, idx);
  gemm_uv<64, 64><<<BN / 64, 256, 0, stream>>>(x2, Wv[2], bv[2], ub, vb);
  hipMemsetAsync(sumP, 0, NPART * 64 * 8, stream);
  hipMemsetAsync(sqP, 0, NPART * 64 * 8, stream);
  combine_max<64><<<BN / 4, 256, 0, stream>>>(ub, vb, idx, hmax, hmin, sumP, sqP);
  bn_finalize<<<1, 256, 0, stream>>>(sumP, sqP, gv[2], bev[2], scale, shift, 64, invMk);
  bn_apply_max<<<(BN * 64 + 255) / 256, 256, 0, stream>>>(hmax, hmin, scale, shift, x3, 63,
                                                          BN * 64);

  // ---- layer 4: C=64 -> D=128 ----
  transpose64<<<tgrid, 256, 0, stream>>>(x3, xT);
  sqnormf_row<<<BN / 4, 256, 0, stream>>>(x3, sqf);
  knn_fused64<<<BN / 16, 256, 0, stream>>>(xT, x3, sqf, idx);
  gemm_uv<64, 128><<<BN / 64, 256, 0, stream>>>(x3, Wv[3], bv[3], ub, vb);
  hipMemsetAsync(sumP, 0, NPART * 128 * 8, stream);
  hipMemsetAsync(sqP, 0, NPART * 128 * 8, stream);
  combine_max<128><<<BN / 2, 256, 0, stream>>>(ub, vb, idx, hmax, hmin, sumP, sqP);
  bn_finalize<<<1, 256, 0, stream>>>(sumP, sqP, gv[3], bev[3], scale, shift, 128, invMk);
  bn_apply_max<<<(BN * 128 + 255) / 256, 256, 0, stream>>>(hmax, hmin, scale, shift, x4, 127,
                                                           BN * 128);

  // ---- final: [BN,320] @ [320,1024], max over n ----
  hipMemsetAsync(sumP, 0, NPART * 1024 * 8, stream);
  hipMemsetAsync(sqP, 0, NPART * 1024 * 8, stream);
  hipMemsetAsync(h5max, 0, B * 1024 * 4, stream);
  hipMemsetAsync(h5min, 0x7f, B * 1024 * 4, stream);
  final_gemm<<<BN / 16, 256, 0, stream>>>(x1, x2, x3, x4, Wv[4], bv[4], h5max, h5min, sumP,
                                          sqP);
  bn_finalize<<<4, 256, 0, stream>>>(sumP, sqP, gv[4], bev[4], scale, shift, 1024,
                                     1.0 / (double)BN);
  final_apply<<<(B * 1024 + 255) / 256, 256, 0, stream>>>(h5max, h5min, scale, shift,
                                                          (float*)d_out);
}